// Round 10
// baseline (312.835 us; speedup 1.0000x reference)
//
#include <hip/hip_runtime.h>
#include <hip/hip_bf16.h>

typedef __bf16 bf16;
typedef __bf16 bf16x8 __attribute__((ext_vector_type(8)));
typedef __bf16 bf16x4 __attribute__((ext_vector_type(4)));
typedef float f32x4 __attribute__((ext_vector_type(4)));

#define SEQ 1024
#define BATCH 8
#define DM 768
#define NH 12
#define HDIM 64
#define DFF 3072
#define NTOK (BATCH*SEQ)

#define AS1 __attribute__((address_space(1)))
#define AS3 __attribute__((address_space(3)))
#define MFMA16(a, b, c) __builtin_amdgcn_mfma_f32_16x16x32_bf16(a, b, c, 0, 0, 0)

// exact tanh-gelu via sigmoid identity: 0.5*(1+tanh(z)) = 1/(1+exp(-2z))
__device__ __forceinline__ float gelu_f(float x) {
  const float c = 0.7978845608028654f;
  float z = c * (x + 0.044715f * x * x * x);
  return x / (1.0f + __expf(-2.0f * z));
}

// all four weight transposes fp32[R][C] -> bf16[C][R] in ONE dispatch
__global__ __launch_bounds__(256) void transpose4_kernel(
    const float* __restrict__ in0, bf16* __restrict__ out0,   // w_attn 768x2304
    const float* __restrict__ in1, bf16* __restrict__ out1,   // w_proj 768x768
    const float* __restrict__ in2, bf16* __restrict__ out2,   // w_fc   768x3072
    const float* __restrict__ in3, bf16* __restrict__ out3) { // w_fc2  3072x768
  __shared__ float tile[32][33];
  int id = blockIdx.x;
  const float* in; bf16* out; int R, C;
  if (id < 1728)      { in = in0; out = out0; R = 768;  C = 2304; }
  else if (id < 2304) { in = in1; out = out1; R = 768;  C = 768;  id -= 1728; }
  else if (id < 4608) { in = in2; out = out2; R = 768;  C = 3072; id -= 2304; }
  else                { in = in3; out = out3; R = 3072; C = 768;  id -= 4608; }
  int nc = C >> 5;
  int c0 = (id % nc) * 32, r0 = (id / nc) * 32;
  int tx = threadIdx.x & 31, ty = threadIdx.x >> 5;  // 32 x 8
  #pragma unroll
  for (int i = 0; i < 4; ++i)
    tile[ty + i * 8][tx] = in[(size_t)(r0 + ty + i * 8) * C + c0 + tx];
  __syncthreads();
  #pragma unroll
  for (int i = 0; i < 4; ++i)
    out[(size_t)(c0 + ty + i * 8) * R + r0 + tx] = (bf16)tile[tx][ty + i * 8];
}

// LayerNorm fp32 [8192][768] -> bf16
__global__ __launch_bounds__(256) void ln_kernel(
    const float* __restrict__ x, const float* __restrict__ g,
    const float* __restrict__ bta, bf16* __restrict__ out) {
  int row = blockIdx.x;
  int tid = threadIdx.x;
  const float* xr = x + (size_t)row * DM;
  float v0 = xr[tid], v1 = xr[tid + 256], v2 = xr[tid + 512];
  float s1 = v0 + v1 + v2;
  float s2 = v0 * v0 + v1 * v1 + v2 * v2;
  #pragma unroll
  for (int m = 32; m >= 1; m >>= 1) {
    s1 += __shfl_xor(s1, m, 64);
    s2 += __shfl_xor(s2, m, 64);
  }
  __shared__ float ps1[4], ps2[4];
  int wid = tid >> 6;
  if ((tid & 63) == 0) { ps1[wid] = s1; ps2[wid] = s2; }
  __syncthreads();
  float t1 = ps1[0] + ps1[1] + ps1[2] + ps1[3];
  float t2 = ps2[0] + ps2[1] + ps2[2] + ps2[3];
  float mean = t1 * (1.0f / DM);
  float var = t2 * (1.0f / DM) - mean * mean;
  float rstd = rsqrtf(var + 1e-5f);
  bf16* orow = out + (size_t)row * DM;
  orow[tid]       = (bf16)((v0 - mean) * rstd * g[tid]       + bta[tid]);
  orow[tid + 256] = (bf16)((v1 - mean) * rstd * g[tid + 256] + bta[tid + 256]);
  orow[tid + 512] = (bf16)((v2 - mean) * rstd * g[tid + 512] + bta[tid + 512]);
}

// proj split-K reduce fused with LN2:
// x1b = bf16(p0 + p1 + b_proj + x);  h = LN(x1b_f32)*g + b   (stats in f32)
__global__ __launch_bounds__(256) void reduce_ln_kernel(
    const float* __restrict__ p0, const float* __restrict__ p1,
    const float* __restrict__ bias, const float* __restrict__ resid,
    const float* __restrict__ g, const float* __restrict__ bta,
    bf16* __restrict__ x1b, bf16* __restrict__ h) {
  int row = blockIdx.x;
  int tid = threadIdx.x;
  size_t base = (size_t)row * DM;
  float v0 = p0[base + tid]       + p1[base + tid]       + bias[tid]       + resid[base + tid];
  float v1 = p0[base + tid + 256] + p1[base + tid + 256] + bias[tid + 256] + resid[base + tid + 256];
  float v2 = p0[base + tid + 512] + p1[base + tid + 512] + bias[tid + 512] + resid[base + tid + 512];
  bf16* xr = x1b + base;
  xr[tid]       = (bf16)v0;
  xr[tid + 256] = (bf16)v1;
  xr[tid + 512] = (bf16)v2;
  float s1 = v0 + v1 + v2;
  float s2 = v0 * v0 + v1 * v1 + v2 * v2;
  #pragma unroll
  for (int m = 32; m >= 1; m >>= 1) {
    s1 += __shfl_xor(s1, m, 64);
    s2 += __shfl_xor(s2, m, 64);
  }
  __shared__ float ps1[4], ps2[4];
  int wid = tid >> 6;
  if ((tid & 63) == 0) { ps1[wid] = s1; ps2[wid] = s2; }
  __syncthreads();
  float t1 = ps1[0] + ps1[1] + ps1[2] + ps1[3];
  float t2 = ps2[0] + ps2[1] + ps2[2] + ps2[3];
  float mean = t1 * (1.0f / DM);
  float var = t2 * (1.0f / DM) - mean * mean;
  float rstd = rsqrtf(var + 1e-5f);
  bf16* orow = h + base;
  orow[tid]       = (bf16)((v0 - mean) * rstd * g[tid]       + bta[tid]);
  orow[tid + 256] = (bf16)((v1 - mean) * rstd * g[tid + 256] + bta[tid + 256]);
  orow[tid + 512] = (bf16)((v2 - mean) * rstd * g[tid + 512] + bta[tid + 512]);
}

// FC2 split-K reduce: out_f32 = p0 + p1 + b_fc2[col] + x1b(bf16)
__global__ __launch_bounds__(256) void reduce_out_kernel(
    const float* __restrict__ p0, const float* __restrict__ p1,
    const float* __restrict__ bias, const bf16* __restrict__ resid,
    float* __restrict__ out) {
  int i = blockIdx.x * 256 + threadIdx.x;   // vec4 index; grid covers NTOK*DM/4
  size_t e = (size_t)i * 4;
  f32x4 a = *(const f32x4*)(p0 + e);
  f32x4 b = *(const f32x4*)(p1 + e);
  f32x4 bs = *(const f32x4*)(bias + (int)(e % DM));
  bf16x4 r = *(const bf16x4*)(resid + e);
  f32x4 o;
  #pragma unroll
  for (int j = 0; j < 4; ++j) o[j] = a[j] + b[j] + bs[j] + (float)r[j];
  *(f32x4*)(out + e) = o;
}

// ---------------------------------------------------------------------------
// gemm8p: 256x256 tile, BK=64, 8 waves (2Mx4N), wave-tile 128x64, acc[8][4].
// 8-PHASE schedule (4 phases per K-tile, 2 K-tiles/iter, guide T3+T4):
// per phase {vmcnt -> barrier -> 8 ds_reads -> issue 2 staging calls ->
// lgkmcnt(0)+sched_barrier -> barrier -> setprio(1) 16 MFMA setprio(0)}.
// Counted vmcnt(2) (never 0 except last tile): staging order per K-tile is
// A0,A2,B0,B1,B2,B3,A1,A3 (slabs of 64 rows x 64 k, 8KB each, 1 call each);
// P0 needs the first 6 (oldest-6 retired -> vmcnt(2)), P1 needs the last 2.
// Staging into buf^1 during tile t is safe: buf^1's readers (tile t-1) all
// passed lgkmcnt(0)+barrier before any wave issues t+1 staging.
// LDS 2x(256x64) per operand = 128 KB -> 1 block/CU; the phase-locked barrier
// pair staggers the 2 waves/SIMD (one in MFMA while other reads/stages).
// Swizzle: 8-slot XOR slot=(kk*4+fq)^(fr&7), pre-swizzled global source
// ((tid&7)^((tid>>3)&7)); row term drops out of bank index -> 2-way max.
// flags bit0 = gelu; bit1 = split-K x2 (col-major decode, raw acc ->
// outF + s*M*N). Epilogue/fragment mapping identical to R7's verified 256^2.
// ---------------------------------------------------------------------------
__global__ __launch_bounds__(512, 2) void gemm8p_kernel(
    const bf16* __restrict__ A, int lda, const bf16* __restrict__ BT,
    const float* __restrict__ bias, const float* __restrict__ residF,
    const bf16* __restrict__ residB,
    float* __restrict__ outF, bf16* __restrict__ outB,
    int N, int K, int flags) {
  __shared__ bf16 As[2][256 * 64];
  __shared__ bf16 Bs[2][256 * 64];
  int tid = threadIdx.x;
  int wid = tid >> 6, lane = tid & 63;
  int nct = N >> 8;
  int nwg = gridDim.x;
  int bid = blockIdx.x;
  int lid = (bid & 7) * (nwg >> 3) + (bid >> 3);   // nwg % 8 == 0 for all uses
  int row0, col0, koff = 0, Keff = K;
  size_t outOff = 0;
  if (flags & 2) {
    int half = nwg >> 1;
    int s = lid / half;
    int r = lid - s * half;
    int nrt = half / nct;
    col0 = (r / nrt) << 8;             // col-major: B-panel pinned per XCD
    row0 = (r % nrt) << 8;
    Keff = K >> 1;
    koff = s * Keff;
    outOff = (size_t)s * ((size_t)nrt << 8) * (size_t)N;
  } else {
    int nrt = nwg / nct;
    col0 = (lid / nrt) << 8;
    row0 = (lid % nrt) << 8;
  }
  int wm = wid >> 2, wn = wid & 3;
  int fr = lane & 15, fq = lane >> 4;
  f32x4 acc[8][4] = {};

  // staging: 512 threads x 16B = 8 KB = one 64-row x 64-k slab per call.
  // thread t: row = t>>3 (0..63), chunk = t&7; source slot pre-swizzled.
  int srow = tid >> 3;
  int ssl = ((tid & 7) ^ ((tid >> 3) & 7)) * 8;
  const bf16* gA = A + (size_t)(row0 + srow) * lda + koff + ssl;
  const bf16* gB = BT + (size_t)(col0 + srow) * K + koff + ssl;
  // LDS dest per call: slab*4096 elems + wave offset (wave w -> rows w*8..w*8+7)
  int ldsw = wid * 512;

  // swizzled read offsets (elem units): slot = (kk*4+fq) ^ (fr&7)
  int aoff0 = (wm * 128 + fr) * 64 + ((0 * 4 + fq) ^ (fr & 7)) * 8;
  int aoff1 = (wm * 128 + fr) * 64 + ((1 * 4 + fq) ^ (fr & 7)) * 8;
  int boff0 = (wn * 64 + fr) * 64 + ((0 * 4 + fq) ^ (fr & 7)) * 8;
  int boff1 = (wn * 64 + fr) * 64 + ((1 * 4 + fq) ^ (fr & 7)) * 8;

  int nt = Keff >> 6;  // 12 (K=768) / 24 (Keff=1536): both even

#define SA(BUF, SLAB, KT)                                                      \
  __builtin_amdgcn_global_load_lds(                                            \
      (const AS1 void*)(gA + (size_t)(SLAB) * 64 * lda + (KT) * 64),           \
      (AS3 void*)(&As[BUF][(SLAB) * 4096 + ldsw]), 16, 0, 0)
#define SB(BUF, SLAB, KT)                                                      \
  __builtin_amdgcn_global_load_lds(                                            \
      (const AS1 void*)(gB + (size_t)(SLAB) * 64 * K + (KT) * 64),             \
      (AS3 void*)(&Bs[BUF][(SLAB) * 4096 + ldsw]), 16, 0, 0)

  // prologue: stage tile 0 only, in the canonical order
  SA(0, 0, 0); SA(0, 2, 0);
  SB(0, 0, 0); SB(0, 1, 0); SB(0, 2, 0); SB(0, 3, 0);
  SA(0, 1, 0); SA(0, 3, 0);

#define TILE(CB, T)                                                            \
  {                                                                            \
    bf16x8 bb0[4], bb1[4], aa[4];                                              \
    /* ---- P0: kk0, m 0..3 ---- */                                            \
    asm volatile("s_waitcnt vmcnt(2)" ::: "memory");                           \
    __builtin_amdgcn_s_barrier();                                              \
    __builtin_amdgcn_sched_barrier(0);                                         \
    _Pragma("unroll")                                                          \
    for (int n = 0; n < 4; ++n) bb0[n] = *(const bf16x8*)&Bs[CB][boff0 + n * 1024]; \
    _Pragma("unroll")                                                          \
    for (int m = 0; m < 4; ++m) aa[m] = *(const bf16x8*)&As[CB][aoff0 + m * 1024]; \
    if ((T) + 1 < nt) { SA((CB) ^ 1, 0, (T) + 1); SA((CB) ^ 1, 2, (T) + 1); }  \
    asm volatile("s_waitcnt lgkmcnt(0)" ::: "memory");                         \
    __builtin_amdgcn_sched_barrier(0);                                         \
    __builtin_amdgcn_s_barrier();                                              \
    __builtin_amdgcn_s_setprio(1);                                             \
    _Pragma("unroll")                                                          \
    for (int m = 0; m < 4; ++m)                                                \
      _Pragma("unroll")                                                        \
      for (int n = 0; n < 4; ++n) acc[m][n] = MFMA16(aa[m], bb0[n], acc[m][n]);\
    __builtin_amdgcn_s_setprio(0);                                             \
    /* ---- P1: kk0, m 4..7 ---- */                                            \
    if ((T) + 1 < nt) asm volatile("s_waitcnt vmcnt(2)" ::: "memory");         \
    else              asm volatile("s_waitcnt vmcnt(0)" ::: "memory");         \
    __builtin_amdgcn_s_barrier();                                              \
    __builtin_amdgcn_sched_barrier(0);                                         \
    _Pragma("unroll")                                                          \
    for (int m = 0; m < 4; ++m) aa[m] = *(const bf16x8*)&As[CB][aoff0 + (4 + m) * 1024]; \
    _Pragma("unroll")                                                          \
    for (int n = 0; n < 4; ++n) bb1[n] = *(const bf16x8*)&Bs[CB][boff1 + n * 1024]; \
    if ((T) + 1 < nt) { SB((CB) ^ 1, 0, (T) + 1); SB((CB) ^ 1, 1, (T) + 1); }  \
    asm volatile("s_waitcnt lgkmcnt(0)" ::: "memory");                         \
    __builtin_amdgcn_sched_barrier(0);                                         \
    __builtin_amdgcn_s_barrier();                                              \
    __builtin_amdgcn_s_setprio(1);                                             \
    _Pragma("unroll")                                                          \
    for (int m = 0; m < 4; ++m)                                                \
      _Pragma("unroll")                                                        \
      for (int n = 0; n < 4; ++n) acc[4 + m][n] = MFMA16(aa[m], bb0[n], acc[4 + m][n]); \
    __builtin_amdgcn_s_setprio(0);                                             \
    /* ---- P2: kk1, m 0..3 ---- */                                            \
    __builtin_amdgcn_s_barrier();                                              \
    __builtin_amdgcn_sched_barrier(0);                                         \
    _Pragma("unroll")                                                          \
    for (int m = 0; m < 4; ++m) aa[m] = *(const bf16x8*)&As[CB][aoff1 + m * 1024]; \
    if ((T) + 1 < nt) { SB((CB) ^ 1, 2, (T) + 1); SB((CB) ^ 1, 3, (T) + 1); }  \
    asm volatile("s_waitcnt lgkmcnt(0)" ::: "memory");                         \
    __builtin_amdgcn_sched_barrier(0);                                         \
    __builtin_amdgcn_s_barrier();                                              \
    __builtin_amdgcn_s_setprio(1);                                             \
    _Pragma("unroll")                                                          \
    for (int m = 0; m < 4; ++m)                                                \
      _Pragma("unroll")                                                        \
      for (int n = 0; n < 4; ++n) acc[m][n] = MFMA16(aa[m], bb1[n], acc[m][n]);\
    __builtin_amdgcn_s_setprio(0);                                             \
    /* ---- P3: kk1, m 4..7 ---- */                                            \
    __builtin_amdgcn_s_barrier();                                              \
    __builtin_amdgcn_sched_barrier(0);                                         \
    _Pragma("unroll")                                                          \
    for (int m = 0; m < 4; ++m) aa[m] = *(const bf16x8*)&As[CB][aoff1 + (4 + m) * 1024]; \
    if ((T) + 1 < nt) { SA((CB) ^ 1, 1, (T) + 1); SA((CB) ^ 1, 3, (T) + 1); }  \
    asm volatile("s_waitcnt lgkmcnt(0)" ::: "memory");                         \
    __builtin_amdgcn_sched_barrier(0);                                         \
    __builtin_amdgcn_s_barrier();                                              \
    __builtin_amdgcn_s_setprio(1);                                             \
    _Pragma("unroll")                                                          \
    for (int m = 0; m < 4; ++m)                                                \
      _Pragma("unroll")                                                        \
      for (int n = 0; n < 4; ++n) acc[4 + m][n] = MFMA16(aa[m], bb1[n], acc[4 + m][n]); \
    __builtin_amdgcn_s_setprio(0);                                             \
  }

  for (int t = 0; t < nt; t += 2) {
    TILE(0, t);
    TILE(1, t + 1);
  }
#undef TILE
#undef SA
#undef SB

  bool gelu = (flags & 1);
  #pragma unroll
  for (int m = 0; m < 8; ++m) {
    #pragma unroll
    for (int n = 0; n < 4; ++n) {
      int col = col0 + wn * 64 + n * 16 + fr;
      float bs = bias ? bias[col] : 0.f;
      #pragma unroll
      for (int r = 0; r < 4; ++r) {
        int row = row0 + wm * 128 + m * 16 + fq * 4 + r;
        float v = acc[m][n][r] + bs;
        if (gelu) v = gelu_f(v);
        if (residF) v += residF[(size_t)row * N + col];
        if (residB) v += (float)residB[(size_t)row * N + col];
        if (outF) outF[outOff + (size_t)row * N + col] = v;
        else outB[(size_t)row * N + col] = (bf16)v;
      }
    }
  }
}

// C[M,N] = A[M,K] @ BT[N,K]^T + bias (+residF f32 | +residB bf16) (+gelu).
// 128x256 tile, BK=32, 8 waves (2Mx4N), wave-tile 64x64, acc[4][4].
// 3-buffer rotation, single barrier per K-step, counted vmcnt(3).
// (R9-proven; kept for QKV and proj split-K.)
__global__ __launch_bounds__(512, 4) void gemm_kernel(
    const bf16* __restrict__ A, int lda, const bf16* __restrict__ BT,
    const float* __restrict__ bias, const float* __restrict__ residF,
    const bf16* __restrict__ residB,
    float* __restrict__ outF, bf16* __restrict__ outB,
    int N, int K, int flags) {
  __shared__ bf16 As[3][128 * 32];
  __shared__ bf16 Bs[3][256 * 32];
  int tid = threadIdx.x;
  int wid = tid >> 6, lane = tid & 63;
  int nct = N >> 8;
  int nwg = gridDim.x;
  int bid = blockIdx.x;
  int lid = ((nwg & 7) == 0) ? ((bid & 7) * (nwg >> 3) + (bid >> 3)) : bid;
  int row0, col0, koff = 0, Keff = K;
  size_t outOff = 0;
  if (flags & 2) {
    int half = nwg >> 1;
    int s = lid / half;
    int r = lid - s * half;
    int nrt = half / nct;              // row tiles
    col0 = (r / nrt) << 8;             // column-major within XCD group
    row0 = (r % nrt) << 7;
    Keff = K >> 1;
    koff = s * Keff;
    outOff = (size_t)s * ((size_t)nrt << 7) * (size_t)N;
  } else {
    row0 = (lid / nct) * 128;
    col0 = (lid % nct) * 256;
  }
  int wm = wid >> 2, wn = wid & 3;
  int fr = lane & 15, fq = lane >> 4;
  f32x4 acc[4][4] = {};

  int srow = tid >> 2;
  int ssl = ((tid & 3) ^ ((tid >> 3) & 3)) * 8;
  const bf16* gA  = A + (size_t)(row0 + srow) * lda + koff + ssl;
  const bf16* gB  = BT + (size_t)(col0 + srow) * K + koff + ssl;
  const bf16* gB2 = gB + (size_t)128 * K;
  int ldsA  = (wid * 16) * 32;          // elems
  int ldsB  = (wid * 16) * 32;
  int ldsB2 = (128 + wid * 16) * 32;

  int RB0 = wn * 64 + 0 * 16 + fr, RB1 = wn * 64 + 1 * 16 + fr;
  int RB2 = wn * 64 + 2 * 16 + fr, RB3 = wn * 64 + 3 * 16 + fr;
  int RA0 = wm * 64 + 0 * 16 + fr, RA1 = wm * 64 + 1 * 16 + fr;
  int RA2 = wm * 64 + 2 * 16 + fr, RA3 = wm * 64 + 3 * 16 + fr;
  int offB0 = RB0 * 32 + (fq ^ ((RB0 >> 1) & 3)) * 8;
  int offB1 = RB1 * 32 + (fq ^ ((RB1 >> 1) & 3)) * 8;
  int offB2 = RB2 * 32 + (fq ^ ((RB2 >> 1) & 3)) * 8;
  int offB3 = RB3 * 32 + (fq ^ ((RB3 >> 1) & 3)) * 8;
  int offA0 = RA0 * 32 + (fq ^ ((RA0 >> 1) & 3)) * 8;
  int offA1 = RA1 * 32 + (fq ^ ((RA1 >> 1) & 3)) * 8;
  int offA2 = RA2 * 32 + (fq ^ ((RA2 >> 1) & 3)) * 8;
  int offA3 = RA3 * 32 + (fq ^ ((RA3 >> 1) & 3)) * 8;

  int nt = Keff >> 5;

  __builtin_amdgcn_global_load_lds((const AS1 void*)(gA), (AS3 void*)(&As[0][ldsA]), 16, 0, 0);
  __builtin_amdgcn_global_load_lds((const AS1 void*)(gB), (AS3 void*)(&Bs[0][ldsB]), 16, 0, 0);
  __builtin_amdgcn_global_load_lds((const AS1 void*)(gB2), (AS3 void*)(&Bs[0][ldsB2]), 16, 0, 0);
  __builtin_amdgcn_global_load_lds((const AS1 void*)(gA + 32), (AS3 void*)(&As[1][ldsA]), 16, 0, 0);
  __builtin_amdgcn_global_load_lds((const AS1 void*)(gB + 32), (AS3 void*)(&Bs[1][ldsB]), 16, 0, 0);
  __builtin_amdgcn_global_load_lds((const AS1 void*)(gB2 + 32), (AS3 void*)(&Bs[1][ldsB2]), 16, 0, 0);

#define KS(CB, T)                                                              \
  {                                                                            \
    if ((T) == nt - 1) asm volatile("s_waitcnt vmcnt(0)" ::: "memory");        \
    else               asm volatile("s_waitcnt vmcnt(3)" ::: "memory");        \
    __builtin_amdgcn_s_barrier();                                              \
    bf16x8 b0 = *(const bf16x8*)&Bs[CB][offB0];                                \
    bf16x8 b1 = *(const bf16x8*)&Bs[CB][offB1];                                \
    bf16x8 b2 = *(const bf16x8*)&Bs[CB][offB2];                                \
    bf16x8 b3 = *(const bf16x8*)&Bs[CB][offB3];                                \
    bf16x8 a0 = *(const bf16x8*)&As[CB][offA0];                                \
    bf16x8 a1 = *(const bf16x8*)&As[CB][offA1];                                \
    if ((T) + 2 < nt)                                                          \
      __builtin_amdgcn_global_load_lds(                                        \
          (const AS1 void*)(gA + ((T) + 2) * 32),                              \
          (AS3 void*)(&As[((CB) + 2) % 3][ldsA]), 16, 0, 0);                   \
    __builtin_amdgcn_s_setprio(1);                                             \
    acc[0][0] = MFMA16(a0, b0, acc[0][0]); acc[0][1] = MFMA16(a0, b1, acc[0][1]); \
    acc[0][2] = MFMA16(a0, b2, acc[0][2]); acc[0][3] = MFMA16(a0, b3, acc[0][3]); \
    acc[1][0] = MFMA16(a1, b0, acc[1][0]); acc[1][1] = MFMA16(a1, b1, acc[1][1]); \
    acc[1][2] = MFMA16(a1, b2, acc[1][2]); acc[1][3] = MFMA16(a1, b3, acc[1][3]); \
    __builtin_amdgcn_s_setprio(0);                                             \
    bf16x8 a2 = *(const bf16x8*)&As[CB][offA2];                                \
    bf16x8 a3 = *(const bf16x8*)&As[CB][offA3];                                \
    if ((T) + 2 < nt) {                                                        \
      __builtin_amdgcn_global_load_lds(                                        \
          (const AS1 void*)(gB + ((T) + 2) * 32),                              \
          (AS3 void*)(&Bs[((CB) + 2) % 3][ldsB]), 16, 0, 0);                   \
      __builtin_amdgcn_global_load_lds(                                        \
          (const AS1 void*)(gB2 + ((T) + 2) * 32),                             \
          (AS3 void*)(&Bs[((CB) + 2) % 3][ldsB2]), 16, 0, 0);                  \
    }                                                                          \
    __builtin_amdgcn_s_setprio(1);                                             \
    acc[2][0] = MFMA16(a2, b0, acc[2][0]); acc[2][1] = MFMA16(a2, b1, acc[2][1]); \
    acc[2][2] = MFMA16(a2, b2, acc[2][2]); acc[2][3] = MFMA16(a2, b3, acc[2][3]); \
    acc[3][0] = MFMA16(a3, b0, acc[3][0]); acc[3][1] = MFMA16(a3, b1, acc[3][1]); \
    acc[3][2] = MFMA16(a3, b2, acc[3][2]); acc[3][3] = MFMA16(a3, b3, acc[3][3]); \
    __builtin_amdgcn_s_setprio(0);                                             \
  }

  for (int t = 0; t < nt; t += 3) {
    KS(0, t);
    KS(1, t + 1);
    KS(2, t + 2);
  }
#undef KS

  bool gelu = (flags & 1);
  #pragma unroll
  for (int m = 0; m < 4; ++m) {
    #pragma unroll
    for (int n = 0; n < 4; ++n) {
      int col = col0 + wn * 64 + n * 16 + fr;
      float bs = bias ? bias[col] : 0.f;
      #pragma unroll
      for (int r = 0; r < 4; ++r) {
        int row = row0 + wm * 64 + m * 16 + fq * 4 + r;
        float v = acc[m][n][r] + bs;
        if (gelu) v = gelu_f(v);
        if (residF) v += residF[(size_t)row * N + col];
        if (residB) v += (float)residB[(size_t)row * N + col];
        if (outF) outF[outOff + (size_t)row * N + col] = v;
        else outB[(size_t)row * N + col] = (bf16)v;
      }
    }
  }
}

// V slice of qkv -> vt[bh][hd][n] (LDS-tiled, coalesced both sides)
__global__ __launch_bounds__(256) void vtrans_kernel(
    const bf16* __restrict__ qkv, bf16* __restrict__ vt) {
  int bh = blockIdx.y;
  int b = bh / NH, h = bh % NH;
  int n0 = blockIdx.x * 64;
  __shared__ bf16 tile[64][65];
  int tx = threadIdx.x & 63, ty = threadIdx.x >> 6;  // 64 x 4
  #pragma unroll
  for (int i = 0; i < 16; ++i) {
    int n = ty + i * 4;
    tile[tx][n] = qkv[(size_t)(b * SEQ + n0 + n) * (3 * DM) + 2 * DM + h * HDIM + tx];
  }
  __syncthreads();
  #pragma unroll
  for (int i = 0; i < 16; ++i) {
    int hd = ty + i * 4;
    vt[((size_t)bh * HDIM + hd) * SEQ + n0 + tx] = tile[hd][tx];
  }
}

// Flash attention: one block per (b,h,64-row q-tile); 4 waves x 16 q-rows.
// K/V LDS double-buffered with counted vmcnt(4) + raw s_barrier.
__global__ __launch_bounds__(256) void attn_kernel(
    bf16* __restrict__ qkv, const bf16* __restrict__ vt,
    const int* __restrict__ pad) {
  __shared__ bf16 Ks[2][64 * 64];
  __shared__ bf16 Vs[2][64 * 64];
  __shared__ bf16 P_lds[4][16 * 72];
  int blk = blockIdx.x;
  int lblk = (blk & 7) * 192 + (blk >> 3);
  int qt = lblk & 15;
  int bh = lblk >> 4;
  int b = bh / NH, h = bh % NH;
  int tid = threadIdx.x, wid = tid >> 6, lane = tid & 63;
  int q0 = qt * 64 + wid * 16;
  int fr = lane & 15;
  int fq = lane >> 4;
  int fk = fq * 8;
  const bf16* qbase = qkv + (size_t)(b * SEQ + q0) * (3 * DM) + h * HDIM;
  bf16* Pw = &P_lds[wid][0];
  bf16x8 qf[2];
  #pragma unroll
  for (int kk = 0; kk < 2; ++kk)
    qf[kk] = *(const bf16x8*)(qbase + (size_t)fr * (3 * DM) + kk * 32 + fk);
  int srow = (wid << 4) + (lane >> 3);
  int sc = ((lane & 7) << 4) ^ ((lane >> 3) << 4);
  const bf16* kSrc = qkv + (size_t)(b * SEQ + srow) * (3 * DM) + DM + h * HDIM + (sc >> 1);
  const bf16* vSrc = vt + ((size_t)bh * HDIM + srow) * SEQ + (sc >> 1);

  auto STAGE = [&](int buf, int kt) {
    const bf16* kS = kSrc + (size_t)kt * 64 * (3 * DM);
    const bf16* vS = vSrc + kt * 64;
    bf16* kD = &Ks[buf][wid * 1024];
    bf16* vD = &Vs[buf][wid * 1024];
    __builtin_amdgcn_global_load_lds((const AS1 void*)kS, (AS3 void*)kD, 16, 0, 0);
    __builtin_amdgcn_global_load_lds((const AS1 void*)(kS + 8 * (3 * DM)), (AS3 void*)(kD + 512), 16, 0, 0);
    __builtin_amdgcn_global_load_lds((const AS1 void*)vS, (AS3 void*)vD, 16, 0, 0);
    __builtin_amdgcn_global_load_lds((const AS1 void*)(vS + 8 * SEQ), (AS3 void*)(vD + 512), 16, 0, 0);
  };

  float lp[4] = {0.f, 0.f, 0.f, 0.f};
  f32x4 oacc[4] = {};
  int padv[4];
  #pragma unroll
  for (int r = 0; r < 4; ++r) padv[r] = pad[b * SEQ + q0 + fq * 4 + r];
  bool anymask = __any(padv[0] == 0 || padv[1] == 0 || padv[2] == 0 || padv[3] == 0);
  int xr = (fr & 7) << 4;

  STAGE(0, 0);
  for (int kt = 0; kt < 16; ++kt) {
    int cur = kt & 1;
    if (kt < 15) STAGE(cur ^ 1, kt + 1);
    if (kt == 15) asm volatile("s_waitcnt vmcnt(0)" ::: "memory");
    else          asm volatile("s_waitcnt vmcnt(4)" ::: "memory");
    __builtin_amdgcn_s_barrier();

    f32x4 s[4];
    #pragma unroll
    for (int nt = 0; nt < 4; ++nt) {
      f32x4 a = {};
      #pragma unroll
      for (int kk = 0; kk < 2; ++kk) {
        int colb = (kk * 64 + fq * 16) ^ xr;
        bf16x8 kf = *(const bf16x8*)&Ks[cur][(nt * 16 + fr) * 64 + (colb >> 1)];
        a = __builtin_amdgcn_mfma_f32_16x16x32_bf16(qf[kk], kf, a, 0, 0, 0);
      }
      s[nt] = a;
    }
    if (anymask) {
      #pragma unroll
      for (int r = 0; r < 4; ++r)
        if (padv[r] == 0) { s[0][r] = 0.f; s[1][r] = 0.f; s[2][r] = 0.f; s[3][r] = 0.f; }
    }
    #pragma unroll
    for (int nt = 0; nt < 4; ++nt)
      #pragma unroll
      for (int r = 0; r < 4; ++r)
        s[nt][r] = __expf(s[nt][r] * 0.125f);
    #pragma unroll
    for (int r = 0; r < 4; ++r)
      lp[r] += (s[0][r] + s[1][r]) + (s[2][r] + s[3][r]);
    #pragma unroll
    for (int nt = 0; nt < 4; ++nt)
      #pragma unroll
      for (int r = 0; r < 4; ++r)
        Pw[(fq * 4 + r) * 72 + nt * 16 + fr] = (bf16)s[nt][r];
    #pragma unroll
    for (int nt = 0; nt < 4; ++nt) {
      #pragma unroll
      for (int ks = 0; ks < 2; ++ks) {
        bf16x8 pf = *(const bf16x8*)&Pw[fr * 72 + ks * 32 + fk];
        int colb = (ks * 64 + fq * 16) ^ xr;
        bf16x8 vf = *(const bf16x8*)&Vs[cur][(nt * 16 + fr) * 64 + (colb >> 1)];
        oacc[nt] = __builtin_amdgcn_mfma_f32_16x16x32_bf16(pf, vf, oacc[nt], 0, 0, 0);
      }
    }
    __builtin_amdgcn_s_barrier();
  }
  #pragma unroll
  for (int r = 0; r < 4; ++r) {
    float l = lp[r];
    #pragma unroll
    for (int msk = 8; msk >= 1; msk >>= 1) l += __shfl_xor(l, msk, 64);
    float inv = 1.0f / l;
    #pragma unroll
    for (int nt = 0; nt < 4; ++nt)
      qkv[(size_t)(b * SEQ + q0 + fq * 4 + r) * (3 * DM) + h * HDIM + nt * 16 + fr] =
          (bf16)(oacc[nt][r] * inv);
  }
}

extern "C" void kernel_launch(void* const* d_in, const int* in_sizes, int n_in,
                              void* d_out, int out_size, void* d_ws, size_t ws_size,
                              hipStream_t stream) {
  const float* x      = (const float*)d_in[0];
  const int*   pad    = (const int*)d_in[1];
  const float* ln1_g  = (const float*)d_in[2];
  const float* ln1_b  = (const float*)d_in[3];
  const float* w_attn = (const float*)d_in[4];
  const float* b_attn = (const float*)d_in[5];
  const float* w_proj = (const float*)d_in[6];
  const float* b_proj = (const float*)d_in[7];
  const float* ln2_g  = (const float*)d_in[8];
  const float* ln2_b  = (const float*)d_in[9];
  const float* w_fc   = (const float*)d_in[10];
  const float* b_fc   = (const float*)d_in[11];
  const float* w_fc2  = (const float*)d_in[12];
  const float* b_fc2  = (const float*)d_in[13];
  float* out = (float*)d_out;

  char* ws = (char*)d_ws;
  size_t off = 0;
  auto alloc = [&](size_t bytes) {
    void* p = ws + off;
    off += (bytes + 255) & ~(size_t)255;
    return p;
  };
  bf16* wT_attn = (bf16*)alloc((size_t)(3 * DM) * DM * 2);
  bf16* wT_proj = (bf16*)alloc((size_t)DM * DM * 2);
  bf16* wT_fc   = (bf16*)alloc((size_t)DFF * DM * 2);
  bf16* wT_fc2  = (bf16*)alloc((size_t)DM * DFF * 2);
  bf16* h       = (bf16*)alloc((size_t)NTOK * DM * 2);        // 12.58 MB
  bf16* qkv     = (bf16*)alloc((size_t)NTOK * (3 * DM) * 2);  // 37.75 MB, contiguous after h
  bf16* vt      = (bf16*)alloc((size_t)BATCH * NH * HDIM * SEQ * 2);
  bf16* x1b     = (bf16*)alloc((size_t)NTOK * DM * 2);
  bf16* act     = (bf16*)alloc((size_t)NTOK * DFF * 2);       // 50.33 MB

  // dead-region reuse for split-K f32 partials (each needs 2*NTOK*DM*4 = 50.33 MB):
  //  - proj partials -> act region (act unwritten until FC)
  //  - FC2 partials  -> h+qkv region (h dead after FC reads it, qkv dead after proj)
  float* partP = (float*)act;
  float* partF = (float*)h;

  // all weight transposes in one dispatch
  transpose4_kernel<<<6912, 256, 0, stream>>>(
      w_attn, wT_attn, w_proj, wT_proj, w_fc, wT_fc, w_fc2, wT_fc2);
  // LN1 (f32 in)
  ln_kernel<<<NTOK, 256, 0, stream>>>(x, ln1_g, ln1_b, h);
  // QKV: 576 tiles (R9-proven kernel)
  gemm_kernel<<<576, 512, 0, stream>>>(
      h, DM, wT_attn, b_attn, nullptr, nullptr, nullptr, qkv, 3 * DM, DM, 0);
  // V transpose (coalesced LDS-tiled)
  vtrans_kernel<<<dim3(SEQ / 64, BATCH * NH), 256, 0, stream>>>(qkv, vt);
  // flash attention (writes O into Q region of qkv)
  attn_kernel<<<BATCH * NH * (SEQ / 64), 256, 0, stream>>>(qkv, vt, pad);
  // proj split-K x2: 384 blocks -> raw partials (R9-proven kernel)
  gemm_kernel<<<384, 512, 0, stream>>>(
      qkv, 3 * DM, wT_proj, nullptr, nullptr, nullptr, partP, nullptr, DM, DM, 2);
  // proj reduce (+bias +resid x) fused with LN2 -> x1b (bf16) + h (LN2 out)
  reduce_ln_kernel<<<NTOK, 256, 0, stream>>>(
      partP, partP + (size_t)NTOK * DM, b_proj, x, ln2_g, ln2_b, x1b, h);
  // FC + gelu -> act (bf16): 256^2 8-phase, 384 blocks
  gemm8p_kernel<<<384, 512, 0, stream>>>(
      h, DM, wT_fc, b_fc, nullptr, nullptr, nullptr, act, DFF, DM, 1);
  // FC2 split-K x2: 256^2 8-phase, 192 blocks -> raw partials
  gemm8p_kernel<<<192, 512, 0, stream>>>(
      act, DFF, wT_fc2, nullptr, nullptr, nullptr, partF, nullptr, DM, DFF, 2);
  // FC2 reduce (+bias +resid x1b) -> out (f32)
  reduce_out_kernel<<<(NTOK * DM) / (4 * 256), 256, 0, stream>>>(
      partF, partF + (size_t)NTOK * DM, b_fc2, x1b, out);
}

// Round 11
// 289.144 us; speedup vs baseline: 1.0819x; 1.0819x over previous
//
#include <hip/hip_runtime.h>
#include <hip/hip_bf16.h>

typedef __bf16 bf16;
typedef __bf16 bf16x8 __attribute__((ext_vector_type(8)));
typedef __bf16 bf16x4 __attribute__((ext_vector_type(4)));
typedef float f32x4 __attribute__((ext_vector_type(4)));

#define SEQ 1024
#define BATCH 8
#define DM 768
#define NH 12
#define HDIM 64
#define DFF 3072
#define NTOK (BATCH*SEQ)

#define AS1 __attribute__((address_space(1)))
#define AS3 __attribute__((address_space(3)))
#define MFMA16(a, b, c) __builtin_amdgcn_mfma_f32_16x16x32_bf16(a, b, c, 0, 0, 0)

// exact tanh-gelu via sigmoid identity: 0.5*(1+tanh(z)) = 1/(1+exp(-2z))
__device__ __forceinline__ float gelu_f(float x) {
  const float c = 0.7978845608028654f;
  float z = c * (x + 0.044715f * x * x * x);
  return x / (1.0f + __expf(-2.0f * z));
}

// all four weight transposes fp32[R][C] -> bf16[C][R] in ONE dispatch
__global__ __launch_bounds__(256) void transpose4_kernel(
    const float* __restrict__ in0, bf16* __restrict__ out0,   // w_attn 768x2304
    const float* __restrict__ in1, bf16* __restrict__ out1,   // w_proj 768x768
    const float* __restrict__ in2, bf16* __restrict__ out2,   // w_fc   768x3072
    const float* __restrict__ in3, bf16* __restrict__ out3) { // w_fc2  3072x768
  __shared__ float tile[32][33];
  int id = blockIdx.x;
  const float* in; bf16* out; int R, C;
  if (id < 1728)      { in = in0; out = out0; R = 768;  C = 2304; }
  else if (id < 2304) { in = in1; out = out1; R = 768;  C = 768;  id -= 1728; }
  else if (id < 4608) { in = in2; out = out2; R = 768;  C = 3072; id -= 2304; }
  else                { in = in3; out = out3; R = 3072; C = 768;  id -= 4608; }
  int nc = C >> 5;
  int c0 = (id % nc) * 32, r0 = (id / nc) * 32;
  int tx = threadIdx.x & 31, ty = threadIdx.x >> 5;  // 32 x 8
  #pragma unroll
  for (int i = 0; i < 4; ++i)
    tile[ty + i * 8][tx] = in[(size_t)(r0 + ty + i * 8) * C + c0 + tx];
  __syncthreads();
  #pragma unroll
  for (int i = 0; i < 4; ++i)
    out[(size_t)(c0 + ty + i * 8) * R + r0 + tx] = (bf16)tile[tx][ty + i * 8];
}

// LayerNorm fp32 [8192][768] -> bf16
__global__ __launch_bounds__(256) void ln_kernel(
    const float* __restrict__ x, const float* __restrict__ g,
    const float* __restrict__ bta, bf16* __restrict__ out) {
  int row = blockIdx.x;
  int tid = threadIdx.x;
  const float* xr = x + (size_t)row * DM;
  float v0 = xr[tid], v1 = xr[tid + 256], v2 = xr[tid + 512];
  float s1 = v0 + v1 + v2;
  float s2 = v0 * v0 + v1 * v1 + v2 * v2;
  #pragma unroll
  for (int m = 32; m >= 1; m >>= 1) {
    s1 += __shfl_xor(s1, m, 64);
    s2 += __shfl_xor(s2, m, 64);
  }
  __shared__ float ps1[4], ps2[4];
  int wid = tid >> 6;
  if ((tid & 63) == 0) { ps1[wid] = s1; ps2[wid] = s2; }
  __syncthreads();
  float t1 = ps1[0] + ps1[1] + ps1[2] + ps1[3];
  float t2 = ps2[0] + ps2[1] + ps2[2] + ps2[3];
  float mean = t1 * (1.0f / DM);
  float var = t2 * (1.0f / DM) - mean * mean;
  float rstd = rsqrtf(var + 1e-5f);
  bf16* orow = out + (size_t)row * DM;
  orow[tid]       = (bf16)((v0 - mean) * rstd * g[tid]       + bta[tid]);
  orow[tid + 256] = (bf16)((v1 - mean) * rstd * g[tid + 256] + bta[tid + 256]);
  orow[tid + 512] = (bf16)((v2 - mean) * rstd * g[tid + 512] + bta[tid + 512]);
}

// proj split-K reduce fused with LN2:
// x1b = bf16(p0 + p1 + b_proj + x);  h = LN(x1b_f32)*g + b   (stats in f32)
__global__ __launch_bounds__(256) void reduce_ln_kernel(
    const float* __restrict__ p0, const float* __restrict__ p1,
    const float* __restrict__ bias, const float* __restrict__ resid,
    const float* __restrict__ g, const float* __restrict__ bta,
    bf16* __restrict__ x1b, bf16* __restrict__ h) {
  int row = blockIdx.x;
  int tid = threadIdx.x;
  size_t base = (size_t)row * DM;
  float v0 = p0[base + tid]       + p1[base + tid]       + bias[tid]       + resid[base + tid];
  float v1 = p0[base + tid + 256] + p1[base + tid + 256] + bias[tid + 256] + resid[base + tid + 256];
  float v2 = p0[base + tid + 512] + p1[base + tid + 512] + bias[tid + 512] + resid[base + tid + 512];
  bf16* xr = x1b + base;
  xr[tid]       = (bf16)v0;
  xr[tid + 256] = (bf16)v1;
  xr[tid + 512] = (bf16)v2;
  float s1 = v0 + v1 + v2;
  float s2 = v0 * v0 + v1 * v1 + v2 * v2;
  #pragma unroll
  for (int m = 32; m >= 1; m >>= 1) {
    s1 += __shfl_xor(s1, m, 64);
    s2 += __shfl_xor(s2, m, 64);
  }
  __shared__ float ps1[4], ps2[4];
  int wid = tid >> 6;
  if ((tid & 63) == 0) { ps1[wid] = s1; ps2[wid] = s2; }
  __syncthreads();
  float t1 = ps1[0] + ps1[1] + ps1[2] + ps1[3];
  float t2 = ps2[0] + ps2[1] + ps2[2] + ps2[3];
  float mean = t1 * (1.0f / DM);
  float var = t2 * (1.0f / DM) - mean * mean;
  float rstd = rsqrtf(var + 1e-5f);
  bf16* orow = h + base;
  orow[tid]       = (bf16)((v0 - mean) * rstd * g[tid]       + bta[tid]);
  orow[tid + 256] = (bf16)((v1 - mean) * rstd * g[tid + 256] + bta[tid + 256]);
  orow[tid + 512] = (bf16)((v2 - mean) * rstd * g[tid + 512] + bta[tid + 512]);
}

// FC2 split-K reduce: out_f32 = p0 + p1 + b_fc2[col] + x1b(bf16)
__global__ __launch_bounds__(256) void reduce_out_kernel(
    const float* __restrict__ p0, const float* __restrict__ p1,
    const float* __restrict__ bias, const bf16* __restrict__ resid,
    float* __restrict__ out) {
  int i = blockIdx.x * 256 + threadIdx.x;   // vec4 index; grid covers NTOK*DM/4
  size_t e = (size_t)i * 4;
  f32x4 a = *(const f32x4*)(p0 + e);
  f32x4 b = *(const f32x4*)(p1 + e);
  f32x4 bs = *(const f32x4*)(bias + (int)(e % DM));
  bf16x4 r = *(const bf16x4*)(resid + e);
  f32x4 o;
  #pragma unroll
  for (int j = 0; j < 4; ++j) o[j] = a[j] + b[j] + bs[j] + (float)r[j];
  *(f32x4*)(out + e) = o;
}

// C[M,N] = A[M,K] @ BT[N,K]^T + bias (+residF f32 | +residB bf16) (+gelu).
// 128x256 tile, BK=32, 8 waves (2Mx4N), wave-tile 64x64, acc[4][4].
// 3-buffer rotation, single barrier per K-step, counted vmcnt(3).
// FINAL structure-family verdict (R2-R10): this is the verified optimum.
//  - 3 blocks/CU of 8-wave blocks: register-impossible (R2: spill, 439us)
//  - 4-wave 128^2 at same residency: worse per-block efficiency (R3: 86us)
//  - 256^2 1-block/CU, coarse schedule: latency-exposed (R7: 82us)
//  - 256^2 1-block/CU, 8-phase fine schedule: still serialized (R10: 94us)
//  - barrier count: neutral (R5); single barrier kept (marginally best)
//  - split-K x2 for N=768 GEMMs + L3-hot reduce: wins (R5 vs R8: 91->77us)
//  - dedicated vtrans beats fused-V scattered epilogue (R1 vs R4)
// The 2-blocks/CU cross-block overlap is what hides staging latency; no
// 1-block schedule expressible here beat it.
// flags bit0 = gelu.
// flags bit1 = split-K x2: col-major decode in XCD swizzle; raw acc ->
//   outF + s*M*N; bias/resid applied by the reduce kernel.
__global__ __launch_bounds__(512, 4) void gemm_kernel(
    const bf16* __restrict__ A, int lda, const bf16* __restrict__ BT,
    const float* __restrict__ bias, const float* __restrict__ residF,
    const bf16* __restrict__ residB,
    float* __restrict__ outF, bf16* __restrict__ outB,
    int N, int K, int flags) {
  __shared__ bf16 As[3][128 * 32];
  __shared__ bf16 Bs[3][256 * 32];
  int tid = threadIdx.x;
  int wid = tid >> 6, lane = tid & 63;
  int nct = N >> 8;
  int nwg = gridDim.x;
  int bid = blockIdx.x;
  int lid = ((nwg & 7) == 0) ? ((bid & 7) * (nwg >> 3) + (bid >> 3)) : bid;
  int row0, col0, koff = 0, Keff = K;
  size_t outOff = 0;
  if (flags & 2) {
    int half = nwg >> 1;
    int s = lid / half;
    int r = lid - s * half;
    int nrt = half / nct;              // row tiles
    col0 = (r / nrt) << 8;             // column-major within XCD group
    row0 = (r % nrt) << 7;
    Keff = K >> 1;
    koff = s * Keff;
    outOff = (size_t)s * ((size_t)nrt << 7) * (size_t)N;
  } else {
    row0 = (lid / nct) * 128;
    col0 = (lid % nct) * 256;
  }
  int wm = wid >> 2, wn = wid & 3;
  int fr = lane & 15, fq = lane >> 4;
  f32x4 acc[4][4] = {};

  int srow = tid >> 2;
  int ssl = ((tid & 3) ^ ((tid >> 3) & 3)) * 8;
  const bf16* gA  = A + (size_t)(row0 + srow) * lda + koff + ssl;
  const bf16* gB  = BT + (size_t)(col0 + srow) * K + koff + ssl;
  const bf16* gB2 = gB + (size_t)128 * K;
  int ldsA  = (wid * 16) * 32;          // elems
  int ldsB  = (wid * 16) * 32;
  int ldsB2 = (128 + wid * 16) * 32;

  int RB0 = wn * 64 + 0 * 16 + fr, RB1 = wn * 64 + 1 * 16 + fr;
  int RB2 = wn * 64 + 2 * 16 + fr, RB3 = wn * 64 + 3 * 16 + fr;
  int RA0 = wm * 64 + 0 * 16 + fr, RA1 = wm * 64 + 1 * 16 + fr;
  int RA2 = wm * 64 + 2 * 16 + fr, RA3 = wm * 64 + 3 * 16 + fr;
  int offB0 = RB0 * 32 + (fq ^ ((RB0 >> 1) & 3)) * 8;
  int offB1 = RB1 * 32 + (fq ^ ((RB1 >> 1) & 3)) * 8;
  int offB2 = RB2 * 32 + (fq ^ ((RB2 >> 1) & 3)) * 8;
  int offB3 = RB3 * 32 + (fq ^ ((RB3 >> 1) & 3)) * 8;
  int offA0 = RA0 * 32 + (fq ^ ((RA0 >> 1) & 3)) * 8;
  int offA1 = RA1 * 32 + (fq ^ ((RA1 >> 1) & 3)) * 8;
  int offA2 = RA2 * 32 + (fq ^ ((RA2 >> 1) & 3)) * 8;
  int offA3 = RA3 * 32 + (fq ^ ((RA3 >> 1) & 3)) * 8;

  int nt = Keff >> 5;  // 24 / 96 / 12 / 48: all % 3 == 0

  __builtin_amdgcn_global_load_lds((const AS1 void*)(gA), (AS3 void*)(&As[0][ldsA]), 16, 0, 0);
  __builtin_amdgcn_global_load_lds((const AS1 void*)(gB), (AS3 void*)(&Bs[0][ldsB]), 16, 0, 0);
  __builtin_amdgcn_global_load_lds((const AS1 void*)(gB2), (AS3 void*)(&Bs[0][ldsB2]), 16, 0, 0);
  __builtin_amdgcn_global_load_lds((const AS1 void*)(gA + 32), (AS3 void*)(&As[1][ldsA]), 16, 0, 0);
  __builtin_amdgcn_global_load_lds((const AS1 void*)(gB + 32), (AS3 void*)(&Bs[1][ldsB]), 16, 0, 0);
  __builtin_amdgcn_global_load_lds((const AS1 void*)(gB2 + 32), (AS3 void*)(&Bs[1][ldsB2]), 16, 0, 0);

#define KS(CB, T)                                                              \
  {                                                                            \
    if ((T) == nt - 1) asm volatile("s_waitcnt vmcnt(0)" ::: "memory");        \
    else               asm volatile("s_waitcnt vmcnt(3)" ::: "memory");        \
    __builtin_amdgcn_s_barrier();                                              \
    bf16x8 b0 = *(const bf16x8*)&Bs[CB][offB0];                                \
    bf16x8 b1 = *(const bf16x8*)&Bs[CB][offB1];                                \
    bf16x8 b2 = *(const bf16x8*)&Bs[CB][offB2];                                \
    bf16x8 b3 = *(const bf16x8*)&Bs[CB][offB3];                                \
    bf16x8 a0 = *(const bf16x8*)&As[CB][offA0];                                \
    bf16x8 a1 = *(const bf16x8*)&As[CB][offA1];                                \
    if ((T) + 2 < nt)                                                          \
      __builtin_amdgcn_global_load_lds(                                        \
          (const AS1 void*)(gA + ((T) + 2) * 32),                              \
          (AS3 void*)(&As[((CB) + 2) % 3][ldsA]), 16, 0, 0);                   \
    __builtin_amdgcn_s_setprio(1);                                             \
    acc[0][0] = MFMA16(a0, b0, acc[0][0]); acc[0][1] = MFMA16(a0, b1, acc[0][1]); \
    acc[0][2] = MFMA16(a0, b2, acc[0][2]); acc[0][3] = MFMA16(a0, b3, acc[0][3]); \
    acc[1][0] = MFMA16(a1, b0, acc[1][0]); acc[1][1] = MFMA16(a1, b1, acc[1][1]); \
    acc[1][2] = MFMA16(a1, b2, acc[1][2]); acc[1][3] = MFMA16(a1, b3, acc[1][3]); \
    __builtin_amdgcn_s_setprio(0);                                             \
    bf16x8 a2 = *(const bf16x8*)&As[CB][offA2];                                \
    bf16x8 a3 = *(const bf16x8*)&As[CB][offA3];                                \
    if ((T) + 2 < nt) {                                                        \
      __builtin_amdgcn_global_load_lds(                                        \
          (const AS1 void*)(gB + ((T) + 2) * 32),                              \
          (AS3 void*)(&Bs[((CB) + 2) % 3][ldsB]), 16, 0, 0);                   \
      __builtin_amdgcn_global_load_lds(                                        \
          (const AS1 void*)(gB2 + ((T) + 2) * 32),                             \
          (AS3 void*)(&Bs[((CB) + 2) % 3][ldsB2]), 16, 0, 0);                  \
    }                                                                          \
    __builtin_amdgcn_s_setprio(1);                                             \
    acc[2][0] = MFMA16(a2, b0, acc[2][0]); acc[2][1] = MFMA16(a2, b1, acc[2][1]); \
    acc[2][2] = MFMA16(a2, b2, acc[2][2]); acc[2][3] = MFMA16(a2, b3, acc[2][3]); \
    acc[3][0] = MFMA16(a3, b0, acc[3][0]); acc[3][1] = MFMA16(a3, b1, acc[3][1]); \
    acc[3][2] = MFMA16(a3, b2, acc[3][2]); acc[3][3] = MFMA16(a3, b3, acc[3][3]); \
    __builtin_amdgcn_s_setprio(0);                                             \
  }

  for (int t = 0; t < nt; t += 3) {
    KS(0, t);
    KS(1, t + 1);
    KS(2, t + 2);
  }
#undef KS

  bool gelu = (flags & 1);
  #pragma unroll
  for (int m = 0; m < 4; ++m) {
    #pragma unroll
    for (int n = 0; n < 4; ++n) {
      int col = col0 + wn * 64 + n * 16 + fr;
      float bs = bias ? bias[col] : 0.f;
      #pragma unroll
      for (int r = 0; r < 4; ++r) {
        int row = row0 + wm * 64 + m * 16 + fq * 4 + r;
        float v = acc[m][n][r] + bs;
        if (gelu) v = gelu_f(v);
        if (residF) v += residF[(size_t)row * N + col];
        if (residB) v += (float)residB[(size_t)row * N + col];
        if (outF) outF[outOff + (size_t)row * N + col] = v;
        else outB[(size_t)row * N + col] = (bf16)v;
      }
    }
  }
}

// V slice of qkv -> vt[bh][hd][n] (LDS-tiled, coalesced both sides --
// measured better than the scattered fused-V GEMM epilogue, R1 vs R4)
__global__ __launch_bounds__(256) void vtrans_kernel(
    const bf16* __restrict__ qkv, bf16* __restrict__ vt) {
  int bh = blockIdx.y;
  int b = bh / NH, h = bh % NH;
  int n0 = blockIdx.x * 64;
  __shared__ bf16 tile[64][65];
  int tx = threadIdx.x & 63, ty = threadIdx.x >> 6;  // 64 x 4
  #pragma unroll
  for (int i = 0; i < 16; ++i) {
    int n = ty + i * 4;
    tile[tx][n] = qkv[(size_t)(b * SEQ + n0 + n) * (3 * DM) + 2 * DM + h * HDIM + tx];
  }
  __syncthreads();
  #pragma unroll
  for (int i = 0; i < 16; ++i) {
    int hd = ty + i * 4;
    vt[((size_t)bh * HDIM + hd) * SEQ + n0 + tx] = tile[hd][tx];
  }
}

// Flash attention: one block per (b,h,64-row q-tile); 4 waves x 16 q-rows.
// K/V LDS double-buffered with counted vmcnt(4) + raw s_barrier.
__global__ __launch_bounds__(256) void attn_kernel(
    bf16* __restrict__ qkv, const bf16* __restrict__ vt,
    const int* __restrict__ pad) {
  __shared__ bf16 Ks[2][64 * 64];
  __shared__ bf16 Vs[2][64 * 64];
  __shared__ bf16 P_lds[4][16 * 72];
  int blk = blockIdx.x;
  int lblk = (blk & 7) * 192 + (blk >> 3);
  int qt = lblk & 15;
  int bh = lblk >> 4;
  int b = bh / NH, h = bh % NH;
  int tid = threadIdx.x, wid = tid >> 6, lane = tid & 63;
  int q0 = qt * 64 + wid * 16;
  int fr = lane & 15;
  int fq = lane >> 4;
  int fk = fq * 8;
  const bf16* qbase = qkv + (size_t)(b * SEQ + q0) * (3 * DM) + h * HDIM;
  bf16* Pw = &P_lds[wid][0];
  bf16x8 qf[2];
  #pragma unroll
  for (int kk = 0; kk < 2; ++kk)
    qf[kk] = *(const bf16x8*)(qbase + (size_t)fr * (3 * DM) + kk * 32 + fk);
  int srow = (wid << 4) + (lane >> 3);
  int sc = ((lane & 7) << 4) ^ ((lane >> 3) << 4);
  const bf16* kSrc = qkv + (size_t)(b * SEQ + srow) * (3 * DM) + DM + h * HDIM + (sc >> 1);
  const bf16* vSrc = vt + ((size_t)bh * HDIM + srow) * SEQ + (sc >> 1);

  auto STAGE = [&](int buf, int kt) {
    const bf16* kS = kSrc + (size_t)kt * 64 * (3 * DM);
    const bf16* vS = vSrc + kt * 64;
    bf16* kD = &Ks[buf][wid * 1024];
    bf16* vD = &Vs[buf][wid * 1024];
    __builtin_amdgcn_global_load_lds((const AS1 void*)kS, (AS3 void*)kD, 16, 0, 0);
    __builtin_amdgcn_global_load_lds((const AS1 void*)(kS + 8 * (3 * DM)), (AS3 void*)(kD + 512), 16, 0, 0);
    __builtin_amdgcn_global_load_lds((const AS1 void*)vS, (AS3 void*)vD, 16, 0, 0);
    __builtin_amdgcn_global_load_lds((const AS1 void*)(vS + 8 * SEQ), (AS3 void*)(vD + 512), 16, 0, 0);
  };

  float lp[4] = {0.f, 0.f, 0.f, 0.f};
  f32x4 oacc[4] = {};
  int padv[4];
  #pragma unroll
  for (int r = 0; r < 4; ++r) padv[r] = pad[b * SEQ + q0 + fq * 4 + r];
  bool anymask = __any(padv[0] == 0 || padv[1] == 0 || padv[2] == 0 || padv[3] == 0);
  int xr = (fr & 7) << 4;

  STAGE(0, 0);
  for (int kt = 0; kt < 16; ++kt) {
    int cur = kt & 1;
    if (kt < 15) STAGE(cur ^ 1, kt + 1);
    if (kt == 15) asm volatile("s_waitcnt vmcnt(0)" ::: "memory");
    else          asm volatile("s_waitcnt vmcnt(4)" ::: "memory");
    __builtin_amdgcn_s_barrier();

    f32x4 s[4];
    #pragma unroll
    for (int nt = 0; nt < 4; ++nt) {
      f32x4 a = {};
      #pragma unroll
      for (int kk = 0; kk < 2; ++kk) {
        int colb = (kk * 64 + fq * 16) ^ xr;
        bf16x8 kf = *(const bf16x8*)&Ks[cur][(nt * 16 + fr) * 64 + (colb >> 1)];
        a = __builtin_amdgcn_mfma_f32_16x16x32_bf16(qf[kk], kf, a, 0, 0, 0);
      }
      s[nt] = a;
    }
    if (anymask) {
      #pragma unroll
      for (int r = 0; r < 4; ++r)
        if (padv[r] == 0) { s[0][r] = 0.f; s[1][r] = 0.f; s[2][r] = 0.f; s[3][r] = 0.f; }
    }
    #pragma unroll
    for (int nt = 0; nt < 4; ++nt)
      #pragma unroll
      for (int r = 0; r < 4; ++r)
        s[nt][r] = __expf(s[nt][r] * 0.125f);
    #pragma unroll
    for (int r = 0; r < 4; ++r)
      lp[r] += (s[0][r] + s[1][r]) + (s[2][r] + s[3][r]);
    #pragma unroll
    for (int nt = 0; nt < 4; ++nt)
      #pragma unroll
      for (int r = 0; r < 4; ++r)
        Pw[(fq * 4 + r) * 72 + nt * 16 + fr] = (bf16)s[nt][r];
    #pragma unroll
    for (int nt = 0; nt < 4; ++nt) {
      #pragma unroll
      for (int ks = 0; ks < 2; ++ks) {
        bf16x8 pf = *(const bf16x8*)&Pw[fr * 72 + ks * 32 + fk];
        int colb = (ks * 64 + fq * 16) ^ xr;
        bf16x8 vf = *(const bf16x8*)&Vs[cur][(nt * 16 + fr) * 64 + (colb >> 1)];
        oacc[nt] = __builtin_amdgcn_mfma_f32_16x16x32_bf16(pf, vf, oacc[nt], 0, 0, 0);
      }
    }
    __builtin_amdgcn_s_barrier();
  }
  #pragma unroll
  for (int r = 0; r < 4; ++r) {
    float l = lp[r];
    #pragma unroll
    for (int msk = 8; msk >= 1; msk >>= 1) l += __shfl_xor(l, msk, 64);
    float inv = 1.0f / l;
    #pragma unroll
    for (int nt = 0; nt < 4; ++nt)
      qkv[(size_t)(b * SEQ + q0 + fq * 4 + r) * (3 * DM) + h * HDIM + nt * 16 + fr] =
          (bf16)(oacc[nt][r] * inv);
  }
}

extern "C" void kernel_launch(void* const* d_in, const int* in_sizes, int n_in,
                              void* d_out, int out_size, void* d_ws, size_t ws_size,
                              hipStream_t stream) {
  const float* x      = (const float*)d_in[0];
  const int*   pad    = (const int*)d_in[1];
  const float* ln1_g  = (const float*)d_in[2];
  const float* ln1_b  = (const float*)d_in[3];
  const float* w_attn = (const float*)d_in[4];
  const float* b_attn = (const float*)d_in[5];
  const float* w_proj = (const float*)d_in[6];
  const float* b_proj = (const float*)d_in[7];
  const float* ln2_g  = (const float*)d_in[8];
  const float* ln2_b  = (const float*)d_in[9];
  const float* w_fc   = (const float*)d_in[10];
  const float* b_fc   = (const float*)d_in[11];
  const float* w_fc2  = (const float*)d_in[12];
  const float* b_fc2  = (const float*)d_in[13];
  float* out = (float*)d_out;

  char* ws = (char*)d_ws;
  size_t off = 0;
  auto alloc = [&](size_t bytes) {
    void* p = ws + off;
    off += (bytes + 255) & ~(size_t)255;
    return p;
  };
  bf16* wT_attn = (bf16*)alloc((size_t)(3 * DM) * DM * 2);
  bf16* wT_proj = (bf16*)alloc((size_t)DM * DM * 2);
  bf16* wT_fc   = (bf16*)alloc((size_t)DFF * DM * 2);
  bf16* wT_fc2  = (bf16*)alloc((size_t)DM * DFF * 2);
  bf16* h       = (bf16*)alloc((size_t)NTOK * DM * 2);        // 12.58 MB
  bf16* qkv     = (bf16*)alloc((size_t)NTOK * (3 * DM) * 2);  // 37.75 MB, contiguous after h
  bf16* vt      = (bf16*)alloc((size_t)BATCH * NH * HDIM * SEQ * 2);
  bf16* x1b     = (bf16*)alloc((size_t)NTOK * DM * 2);
  bf16* act     = (bf16*)alloc((size_t)NTOK * DFF * 2);       // 50.33 MB

  // dead-region reuse for split-K f32 partials (each needs 2*NTOK*DM*4 = 50.33 MB):
  //  - proj partials -> act region (act unwritten until FC)
  //  - FC2 partials  -> h+qkv region (h dead after FC reads it, qkv dead after proj)
  float* partP = (float*)act;
  float* partF = (float*)h;

  // all weight transposes in one dispatch
  transpose4_kernel<<<6912, 256, 0, stream>>>(
      w_attn, wT_attn, w_proj, wT_proj, w_fc, wT_fc, w_fc2, wT_fc2);
  // LN1 (f32 in)
  ln_kernel<<<NTOK, 256, 0, stream>>>(x, ln1_g, ln1_b, h);
  // QKV: 576 tiles
  gemm_kernel<<<576, 512, 0, stream>>>(
      h, DM, wT_attn, b_attn, nullptr, nullptr, nullptr, qkv, 3 * DM, DM, 0);
  // V transpose (coalesced LDS-tiled)
  vtrans_kernel<<<dim3(SEQ / 64, BATCH * NH), 256, 0, stream>>>(qkv, vt);
  // flash attention (writes O into Q region of qkv)
  attn_kernel<<<BATCH * NH * (SEQ / 64), 256, 0, stream>>>(qkv, vt, pad);
  // proj split-K x2: 384 blocks -> raw partials (no bias/resid yet)
  gemm_kernel<<<384, 512, 0, stream>>>(
      qkv, 3 * DM, wT_proj, nullptr, nullptr, nullptr, partP, nullptr, DM, DM, 2);
  // proj reduce (+bias +resid x) fused with LN2 -> x1b (bf16) + h (LN2 out)
  reduce_ln_kernel<<<NTOK, 256, 0, stream>>>(
      partP, partP + (size_t)NTOK * DM, b_proj, x, ln2_g, ln2_b, x1b, h);
  // FC + gelu -> act (bf16): 768 tiles
  gemm_kernel<<<768, 512, 0, stream>>>(
      h, DM, wT_fc, b_fc, nullptr, nullptr, nullptr, act, DFF, DM, 1);
  // FC2 split-K x2: 384 blocks -> raw partials into h+qkv region
  gemm_kernel<<<384, 512, 0, stream>>>(
      act, DFF, wT_fc2, nullptr, nullptr, nullptr, partF, nullptr, DM, DFF, 2);
  // FC2 reduce (+bias +resid x1b) -> out (f32)
  reduce_out_kernel<<<(NTOK * DM) / (4 * 256), 256, 0, stream>>>(
      partF, partF + (size_t)NTOK * DM, b_fc2, x1b, out);
}

// Round 12
// 283.561 us; speedup vs baseline: 1.1032x; 1.0197x over previous
//
#include <hip/hip_runtime.h>
#include <hip/hip_bf16.h>

typedef __bf16 bf16;
typedef __bf16 bf16x8 __attribute__((ext_vector_type(8)));
typedef __bf16 bf16x4 __attribute__((ext_vector_type(4)));
typedef float f32x4 __attribute__((ext_vector_type(4)));

#define SEQ 1024
#define BATCH 8
#define DM 768
#define NH 12
#define HDIM 64
#define DFF 3072
#define NTOK (BATCH*SEQ)

#define AS1 __attribute__((address_space(1)))
#define AS3 __attribute__((address_space(3)))
#define MFMA16(a, b, c) __builtin_amdgcn_mfma_f32_16x16x32_bf16(a, b, c, 0, 0, 0)

// exact tanh-gelu via sigmoid identity: 0.5*(1+tanh(z)) = 1/(1+exp(-2z))
__device__ __forceinline__ float gelu_f(float x) {
  const float c = 0.7978845608028654f;
  float z = c * (x + 0.044715f * x * x * x);
  return x / (1.0f + __expf(-2.0f * z));
}

// all four weight transposes fp32[R][C] -> bf16[C][R] in ONE dispatch
__global__ __launch_bounds__(256) void transpose4_kernel(
    const float* __restrict__ in0, bf16* __restrict__ out0,   // w_attn 768x2304
    const float* __restrict__ in1, bf16* __restrict__ out1,   // w_proj 768x768
    const float* __restrict__ in2, bf16* __restrict__ out2,   // w_fc   768x3072
    const float* __restrict__ in3, bf16* __restrict__ out3) { // w_fc2  3072x768
  __shared__ float tile[32][33];
  int id = blockIdx.x;
  const float* in; bf16* out; int R, C;
  if (id < 1728)      { in = in0; out = out0; R = 768;  C = 2304; }
  else if (id < 2304) { in = in1; out = out1; R = 768;  C = 768;  id -= 1728; }
  else if (id < 4608) { in = in2; out = out2; R = 768;  C = 3072; id -= 2304; }
  else                { in = in3; out = out3; R = 3072; C = 768;  id -= 4608; }
  int nc = C >> 5;
  int c0 = (id % nc) * 32, r0 = (id / nc) * 32;
  int tx = threadIdx.x & 31, ty = threadIdx.x >> 5;  // 32 x 8
  #pragma unroll
  for (int i = 0; i < 4; ++i)
    tile[ty + i * 8][tx] = in[(size_t)(r0 + ty + i * 8) * C + c0 + tx];
  __syncthreads();
  #pragma unroll
  for (int i = 0; i < 4; ++i)
    out[(size_t)(c0 + ty + i * 8) * R + r0 + tx] = (bf16)tile[tx][ty + i * 8];
}

// LayerNorm fp32 [8192][768] -> bf16
__global__ __launch_bounds__(256) void ln_kernel(
    const float* __restrict__ x, const float* __restrict__ g,
    const float* __restrict__ bta, bf16* __restrict__ out) {
  int row = blockIdx.x;
  int tid = threadIdx.x;
  const float* xr = x + (size_t)row * DM;
  float v0 = xr[tid], v1 = xr[tid + 256], v2 = xr[tid + 512];
  float s1 = v0 + v1 + v2;
  float s2 = v0 * v0 + v1 * v1 + v2 * v2;
  #pragma unroll
  for (int m = 32; m >= 1; m >>= 1) {
    s1 += __shfl_xor(s1, m, 64);
    s2 += __shfl_xor(s2, m, 64);
  }
  __shared__ float ps1[4], ps2[4];
  int wid = tid >> 6;
  if ((tid & 63) == 0) { ps1[wid] = s1; ps2[wid] = s2; }
  __syncthreads();
  float t1 = ps1[0] + ps1[1] + ps1[2] + ps1[3];
  float t2 = ps2[0] + ps2[1] + ps2[2] + ps2[3];
  float mean = t1 * (1.0f / DM);
  float var = t2 * (1.0f / DM) - mean * mean;
  float rstd = rsqrtf(var + 1e-5f);
  bf16* orow = out + (size_t)row * DM;
  orow[tid]       = (bf16)((v0 - mean) * rstd * g[tid]       + bta[tid]);
  orow[tid + 256] = (bf16)((v1 - mean) * rstd * g[tid + 256] + bta[tid + 256]);
  orow[tid + 512] = (bf16)((v2 - mean) * rstd * g[tid + 512] + bta[tid + 512]);
}

// proj split-K reduce fused with LN2 (bf16 partials, vectorized bf16x4):
// x1b = bf16(p0 + p1 + b_proj + x);  h = LN(x1b_f32)*g + b   (stats in f32)
__global__ __launch_bounds__(256) void reduce_ln_kernel(
    const bf16* __restrict__ p0, const bf16* __restrict__ p1,
    const float* __restrict__ bias, const float* __restrict__ resid,
    const float* __restrict__ g, const float* __restrict__ bta,
    bf16* __restrict__ x1b, bf16* __restrict__ h) {
  int row = blockIdx.x;
  int tid = threadIdx.x;
  size_t base = (size_t)row * DM;
  float v[4] = {0.f, 0.f, 0.f, 0.f};
  if (tid < 192) {
    bf16x4 a  = *(const bf16x4*)(p0 + base + tid * 4);
    bf16x4 b  = *(const bf16x4*)(p1 + base + tid * 4);
    f32x4  rs = *(const f32x4*)(resid + base + tid * 4);
    f32x4  bs = *(const f32x4*)(bias + tid * 4);
    bf16x4 o;
    #pragma unroll
    for (int j = 0; j < 4; ++j) {
      v[j] = (float)a[j] + (float)b[j] + bs[j] + rs[j];
      o[j] = (bf16)v[j];
    }
    *(bf16x4*)(x1b + base + tid * 4) = o;
  }
  float s1 = (v[0] + v[1]) + (v[2] + v[3]);
  float s2 = (v[0] * v[0] + v[1] * v[1]) + (v[2] * v[2] + v[3] * v[3]);
  #pragma unroll
  for (int m = 32; m >= 1; m >>= 1) {
    s1 += __shfl_xor(s1, m, 64);
    s2 += __shfl_xor(s2, m, 64);
  }
  __shared__ float ps1[4], ps2[4];
  int wid = tid >> 6;
  if ((tid & 63) == 0) { ps1[wid] = s1; ps2[wid] = s2; }
  __syncthreads();
  float t1 = ps1[0] + ps1[1] + ps1[2] + ps1[3];
  float t2 = ps2[0] + ps2[1] + ps2[2] + ps2[3];
  float mean = t1 * (1.0f / DM);
  float var = t2 * (1.0f / DM) - mean * mean;
  float rstd = rsqrtf(var + 1e-5f);
  if (tid < 192) {
    bf16x4 o;
    #pragma unroll
    for (int j = 0; j < 4; ++j)
      o[j] = (bf16)((v[j] - mean) * rstd * g[tid * 4 + j] + bta[tid * 4 + j]);
    *(bf16x4*)(h + base + tid * 4) = o;
  }
}

// FC2 split-K reduce (bf16 partials): out_f32 = p0 + p1 + b_fc2[col] + x1b(bf16)
__global__ __launch_bounds__(256) void reduce_out_kernel(
    const bf16* __restrict__ p0, const bf16* __restrict__ p1,
    const float* __restrict__ bias, const bf16* __restrict__ resid,
    float* __restrict__ out) {
  int i = blockIdx.x * 256 + threadIdx.x;   // vec4 index; grid covers NTOK*DM/4
  size_t e = (size_t)i * 4;
  bf16x4 a = *(const bf16x4*)(p0 + e);
  bf16x4 b = *(const bf16x4*)(p1 + e);
  f32x4 bs = *(const f32x4*)(bias + (int)(e % DM));
  bf16x4 r = *(const bf16x4*)(resid + e);
  f32x4 o;
  #pragma unroll
  for (int j = 0; j < 4; ++j) o[j] = (float)a[j] + (float)b[j] + bs[j] + (float)r[j];
  *(f32x4*)(out + e) = o;
}

// C[M,N] = A[M,K] @ BT[N,K]^T + bias (+residF f32 | +residB bf16) (+gelu).
// 128x256 tile, BK=32, 8 waves (2Mx4N), wave-tile 64x64, acc[4][4].
// 3-buffer rotation, single barrier per K-step, counted vmcnt(3).
// FINAL structure-family verdict (R2-R10): this is the verified optimum.
//  - 3 blocks/CU of 8-wave blocks: register-impossible (R2: spill, 439us)
//  - 4-wave 128^2 at same residency: worse per-block efficiency (R3: 86us)
//  - 256^2 1-block/CU, coarse schedule: latency-exposed (R7: 82us)
//  - 256^2 1-block/CU, 8-phase fine schedule: still serialized (R10: 94us)
//  - barrier count: neutral (R5); single barrier kept (marginally best)
//  - split-K x2 for N=768 GEMMs + L3-hot reduce: wins (R5 vs R8: 91->77us)
//  - dedicated vtrans beats fused-V scattered epilogue (R1 vs R4)
// The 2-blocks/CU cross-block overlap is what hides staging latency; no
// 1-block schedule expressible here beat it.
// flags bit0 = gelu.
// flags bit1 = split-K x2: col-major decode in XCD swizzle; raw acc ->
//   (outF|outB) + s*M*N; bias/resid applied by the reduce kernel.
//   R12: bf16 partials supported via outB path (halves partial HBM traffic).
__global__ __launch_bounds__(512, 4) void gemm_kernel(
    const bf16* __restrict__ A, int lda, const bf16* __restrict__ BT,
    const float* __restrict__ bias, const float* __restrict__ residF,
    const bf16* __restrict__ residB,
    float* __restrict__ outF, bf16* __restrict__ outB,
    int N, int K, int flags) {
  __shared__ bf16 As[3][128 * 32];
  __shared__ bf16 Bs[3][256 * 32];
  int tid = threadIdx.x;
  int wid = tid >> 6, lane = tid & 63;
  int nct = N >> 8;
  int nwg = gridDim.x;
  int bid = blockIdx.x;
  int lid = ((nwg & 7) == 0) ? ((bid & 7) * (nwg >> 3) + (bid >> 3)) : bid;
  int row0, col0, koff = 0, Keff = K;
  size_t outOff = 0;
  if (flags & 2) {
    int half = nwg >> 1;
    int s = lid / half;
    int r = lid - s * half;
    int nrt = half / nct;              // row tiles
    col0 = (r / nrt) << 8;             // column-major within XCD group
    row0 = (r % nrt) << 7;
    Keff = K >> 1;
    koff = s * Keff;
    outOff = (size_t)s * ((size_t)nrt << 7) * (size_t)N;
  } else {
    row0 = (lid / nct) * 128;
    col0 = (lid % nct) * 256;
  }
  int wm = wid >> 2, wn = wid & 3;
  int fr = lane & 15, fq = lane >> 4;
  f32x4 acc[4][4] = {};

  int srow = tid >> 2;
  int ssl = ((tid & 3) ^ ((tid >> 3) & 3)) * 8;
  const bf16* gA  = A + (size_t)(row0 + srow) * lda + koff + ssl;
  const bf16* gB  = BT + (size_t)(col0 + srow) * K + koff + ssl;
  const bf16* gB2 = gB + (size_t)128 * K;
  int ldsA  = (wid * 16) * 32;          // elems
  int ldsB  = (wid * 16) * 32;
  int ldsB2 = (128 + wid * 16) * 32;

  int RB0 = wn * 64 + 0 * 16 + fr, RB1 = wn * 64 + 1 * 16 + fr;
  int RB2 = wn * 64 + 2 * 16 + fr, RB3 = wn * 64 + 3 * 16 + fr;
  int RA0 = wm * 64 + 0 * 16 + fr, RA1 = wm * 64 + 1 * 16 + fr;
  int RA2 = wm * 64 + 2 * 16 + fr, RA3 = wm * 64 + 3 * 16 + fr;
  int offB0 = RB0 * 32 + (fq ^ ((RB0 >> 1) & 3)) * 8;
  int offB1 = RB1 * 32 + (fq ^ ((RB1 >> 1) & 3)) * 8;
  int offB2 = RB2 * 32 + (fq ^ ((RB2 >> 1) & 3)) * 8;
  int offB3 = RB3 * 32 + (fq ^ ((RB3 >> 1) & 3)) * 8;
  int offA0 = RA0 * 32 + (fq ^ ((RA0 >> 1) & 3)) * 8;
  int offA1 = RA1 * 32 + (fq ^ ((RA1 >> 1) & 3)) * 8;
  int offA2 = RA2 * 32 + (fq ^ ((RA2 >> 1) & 3)) * 8;
  int offA3 = RA3 * 32 + (fq ^ ((RA3 >> 1) & 3)) * 8;

  int nt = Keff >> 5;  // 24 / 96 / 12 / 48: all % 3 == 0

  __builtin_amdgcn_global_load_lds((const AS1 void*)(gA), (AS3 void*)(&As[0][ldsA]), 16, 0, 0);
  __builtin_amdgcn_global_load_lds((const AS1 void*)(gB), (AS3 void*)(&Bs[0][ldsB]), 16, 0, 0);
  __builtin_amdgcn_global_load_lds((const AS1 void*)(gB2), (AS3 void*)(&Bs[0][ldsB2]), 16, 0, 0);
  __builtin_amdgcn_global_load_lds((const AS1 void*)(gA + 32), (AS3 void*)(&As[1][ldsA]), 16, 0, 0);
  __builtin_amdgcn_global_load_lds((const AS1 void*)(gB + 32), (AS3 void*)(&Bs[1][ldsB]), 16, 0, 0);
  __builtin_amdgcn_global_load_lds((const AS1 void*)(gB2 + 32), (AS3 void*)(&Bs[1][ldsB2]), 16, 0, 0);

#define KS(CB, T)                                                              \
  {                                                                            \
    if ((T) == nt - 1) asm volatile("s_waitcnt vmcnt(0)" ::: "memory");        \
    else               asm volatile("s_waitcnt vmcnt(3)" ::: "memory");        \
    __builtin_amdgcn_s_barrier();                                              \
    bf16x8 b0 = *(const bf16x8*)&Bs[CB][offB0];                                \
    bf16x8 b1 = *(const bf16x8*)&Bs[CB][offB1];                                \
    bf16x8 b2 = *(const bf16x8*)&Bs[CB][offB2];                                \
    bf16x8 b3 = *(const bf16x8*)&Bs[CB][offB3];                                \
    bf16x8 a0 = *(const bf16x8*)&As[CB][offA0];                                \
    bf16x8 a1 = *(const bf16x8*)&As[CB][offA1];                                \
    if ((T) + 2 < nt)                                                          \
      __builtin_amdgcn_global_load_lds(                                        \
          (const AS1 void*)(gA + ((T) + 2) * 32),                              \
          (AS3 void*)(&As[((CB) + 2) % 3][ldsA]), 16, 0, 0);                   \
    __builtin_amdgcn_s_setprio(1);                                             \
    acc[0][0] = MFMA16(a0, b0, acc[0][0]); acc[0][1] = MFMA16(a0, b1, acc[0][1]); \
    acc[0][2] = MFMA16(a0, b2, acc[0][2]); acc[0][3] = MFMA16(a0, b3, acc[0][3]); \
    acc[1][0] = MFMA16(a1, b0, acc[1][0]); acc[1][1] = MFMA16(a1, b1, acc[1][1]); \
    acc[1][2] = MFMA16(a1, b2, acc[1][2]); acc[1][3] = MFMA16(a1, b3, acc[1][3]); \
    __builtin_amdgcn_s_setprio(0);                                             \
    bf16x8 a2 = *(const bf16x8*)&As[CB][offA2];                                \
    bf16x8 a3 = *(const bf16x8*)&As[CB][offA3];                                \
    if ((T) + 2 < nt) {                                                        \
      __builtin_amdgcn_global_load_lds(                                        \
          (const AS1 void*)(gB + ((T) + 2) * 32),                              \
          (AS3 void*)(&Bs[((CB) + 2) % 3][ldsB]), 16, 0, 0);                   \
      __builtin_amdgcn_global_load_lds(                                        \
          (const AS1 void*)(gB2 + ((T) + 2) * 32),                             \
          (AS3 void*)(&Bs[((CB) + 2) % 3][ldsB2]), 16, 0, 0);                  \
    }                                                                          \
    __builtin_amdgcn_s_setprio(1);                                             \
    acc[2][0] = MFMA16(a2, b0, acc[2][0]); acc[2][1] = MFMA16(a2, b1, acc[2][1]); \
    acc[2][2] = MFMA16(a2, b2, acc[2][2]); acc[2][3] = MFMA16(a2, b3, acc[2][3]); \
    acc[3][0] = MFMA16(a3, b0, acc[3][0]); acc[3][1] = MFMA16(a3, b1, acc[3][1]); \
    acc[3][2] = MFMA16(a3, b2, acc[3][2]); acc[3][3] = MFMA16(a3, b3, acc[3][3]); \
    __builtin_amdgcn_s_setprio(0);                                             \
  }

  for (int t = 0; t < nt; t += 3) {
    KS(0, t);
    KS(1, t + 1);
    KS(2, t + 2);
  }
#undef KS

  bool gelu = (flags & 1);
  #pragma unroll
  for (int m = 0; m < 4; ++m) {
    #pragma unroll
    for (int n = 0; n < 4; ++n) {
      int col = col0 + wn * 64 + n * 16 + fr;
      float bs = bias ? bias[col] : 0.f;
      #pragma unroll
      for (int r = 0; r < 4; ++r) {
        int row = row0 + wm * 64 + m * 16 + fq * 4 + r;
        float v = acc[m][n][r] + bs;
        if (gelu) v = gelu_f(v);
        if (residF) v += residF[(size_t)row * N + col];
        if (residB) v += (float)residB[(size_t)row * N + col];
        if (outF) outF[outOff + (size_t)row * N + col] = v;
        else outB[outOff + (size_t)row * N + col] = (bf16)v;
      }
    }
  }
}

// V slice of qkv -> vt[bh][hd][n] (LDS-tiled, coalesced both sides --
// measured better than the scattered fused-V GEMM epilogue, R1 vs R4)
__global__ __launch_bounds__(256) void vtrans_kernel(
    const bf16* __restrict__ qkv, bf16* __restrict__ vt) {
  int bh = blockIdx.y;
  int b = bh / NH, h = bh % NH;
  int n0 = blockIdx.x * 64;
  __shared__ bf16 tile[64][65];
  int tx = threadIdx.x & 63, ty = threadIdx.x >> 6;  // 64 x 4
  #pragma unroll
  for (int i = 0; i < 16; ++i) {
    int n = ty + i * 4;
    tile[tx][n] = qkv[(size_t)(b * SEQ + n0 + n) * (3 * DM) + 2 * DM + h * HDIM + tx];
  }
  __syncthreads();
  #pragma unroll
  for (int i = 0; i < 16; ++i) {
    int hd = ty + i * 4;
    vt[((size_t)bh * HDIM + hd) * SEQ + n0 + tx] = tile[hd][tx];
  }
}

// Flash attention: one block per (b,h,64-row q-tile); 4 waves x 16 q-rows.
// K/V LDS double-buffered with counted vmcnt(4) + raw s_barrier.
__global__ __launch_bounds__(256) void attn_kernel(
    bf16* __restrict__ qkv, const bf16* __restrict__ vt,
    const int* __restrict__ pad) {
  __shared__ bf16 Ks[2][64 * 64];
  __shared__ bf16 Vs[2][64 * 64];
  __shared__ bf16 P_lds[4][16 * 72];
  int blk = blockIdx.x;
  int lblk = (blk & 7) * 192 + (blk >> 3);
  int qt = lblk & 15;
  int bh = lblk >> 4;
  int b = bh / NH, h = bh % NH;
  int tid = threadIdx.x, wid = tid >> 6, lane = tid & 63;
  int q0 = qt * 64 + wid * 16;
  int fr = lane & 15;
  int fq = lane >> 4;
  int fk = fq * 8;
  const bf16* qbase = qkv + (size_t)(b * SEQ + q0) * (3 * DM) + h * HDIM;
  bf16* Pw = &P_lds[wid][0];
  bf16x8 qf[2];
  #pragma unroll
  for (int kk = 0; kk < 2; ++kk)
    qf[kk] = *(const bf16x8*)(qbase + (size_t)fr * (3 * DM) + kk * 32 + fk);
  int srow = (wid << 4) + (lane >> 3);
  int sc = ((lane & 7) << 4) ^ ((lane >> 3) << 4);
  const bf16* kSrc = qkv + (size_t)(b * SEQ + srow) * (3 * DM) + DM + h * HDIM + (sc >> 1);
  const bf16* vSrc = vt + ((size_t)bh * HDIM + srow) * SEQ + (sc >> 1);

  auto STAGE = [&](int buf, int kt) {
    const bf16* kS = kSrc + (size_t)kt * 64 * (3 * DM);
    const bf16* vS = vSrc + kt * 64;
    bf16* kD = &Ks[buf][wid * 1024];
    bf16* vD = &Vs[buf][wid * 1024];
    __builtin_amdgcn_global_load_lds((const AS1 void*)kS, (AS3 void*)kD, 16, 0, 0);
    __builtin_amdgcn_global_load_lds((const AS1 void*)(kS + 8 * (3 * DM)), (AS3 void*)(kD + 512), 16, 0, 0);
    __builtin_amdgcn_global_load_lds((const AS1 void*)vS, (AS3 void*)vD, 16, 0, 0);
    __builtin_amdgcn_global_load_lds((const AS1 void*)(vS + 8 * SEQ), (AS3 void*)(vD + 512), 16, 0, 0);
  };

  float lp[4] = {0.f, 0.f, 0.f, 0.f};
  f32x4 oacc[4] = {};
  int padv[4];
  #pragma unroll
  for (int r = 0; r < 4; ++r) padv[r] = pad[b * SEQ + q0 + fq * 4 + r];
  bool anymask = __any(padv[0] == 0 || padv[1] == 0 || padv[2] == 0 || padv[3] == 0);
  int xr = (fr & 7) << 4;

  STAGE(0, 0);
  for (int kt = 0; kt < 16; ++kt) {
    int cur = kt & 1;
    if (kt < 15) STAGE(cur ^ 1, kt + 1);
    if (kt == 15) asm volatile("s_waitcnt vmcnt(0)" ::: "memory");
    else          asm volatile("s_waitcnt vmcnt(4)" ::: "memory");
    __builtin_amdgcn_s_barrier();

    f32x4 s[4];
    #pragma unroll
    for (int nt = 0; nt < 4; ++nt) {
      f32x4 a = {};
      #pragma unroll
      for (int kk = 0; kk < 2; ++kk) {
        int colb = (kk * 64 + fq * 16) ^ xr;
        bf16x8 kf = *(const bf16x8*)&Ks[cur][(nt * 16 + fr) * 64 + (colb >> 1)];
        a = __builtin_amdgcn_mfma_f32_16x16x32_bf16(qf[kk], kf, a, 0, 0, 0);
      }
      s[nt] = a;
    }
    if (anymask) {
      #pragma unroll
      for (int r = 0; r < 4; ++r)
        if (padv[r] == 0) { s[0][r] = 0.f; s[1][r] = 0.f; s[2][r] = 0.f; s[3][r] = 0.f; }
    }
    #pragma unroll
    for (int nt = 0; nt < 4; ++nt)
      #pragma unroll
      for (int r = 0; r < 4; ++r)
        s[nt][r] = __expf(s[nt][r] * 0.125f);
    #pragma unroll
    for (int r = 0; r < 4; ++r)
      lp[r] += (s[0][r] + s[1][r]) + (s[2][r] + s[3][r]);
    #pragma unroll
    for (int nt = 0; nt < 4; ++nt)
      #pragma unroll
      for (int r = 0; r < 4; ++r)
        Pw[(fq * 4 + r) * 72 + nt * 16 + fr] = (bf16)s[nt][r];
    #pragma unroll
    for (int nt = 0; nt < 4; ++nt) {
      #pragma unroll
      for (int ks = 0; ks < 2; ++ks) {
        bf16x8 pf = *(const bf16x8*)&Pw[fr * 72 + ks * 32 + fk];
        int colb = (ks * 64 + fq * 16) ^ xr;
        bf16x8 vf = *(const bf16x8*)&Vs[cur][(nt * 16 + fr) * 64 + (colb >> 1)];
        oacc[nt] = __builtin_amdgcn_mfma_f32_16x16x32_bf16(pf, vf, oacc[nt], 0, 0, 0);
      }
    }
    __builtin_amdgcn_s_barrier();
  }
  #pragma unroll
  for (int r = 0; r < 4; ++r) {
    float l = lp[r];
    #pragma unroll
    for (int msk = 8; msk >= 1; msk >>= 1) l += __shfl_xor(l, msk, 64);
    float inv = 1.0f / l;
    #pragma unroll
    for (int nt = 0; nt < 4; ++nt)
      qkv[(size_t)(b * SEQ + q0 + fq * 4 + r) * (3 * DM) + h * HDIM + nt * 16 + fr] =
          (bf16)(oacc[nt][r] * inv);
  }
}

extern "C" void kernel_launch(void* const* d_in, const int* in_sizes, int n_in,
                              void* d_out, int out_size, void* d_ws, size_t ws_size,
                              hipStream_t stream) {
  const float* x      = (const float*)d_in[0];
  const int*   pad    = (const int*)d_in[1];
  const float* ln1_g  = (const float*)d_in[2];
  const float* ln1_b  = (const float*)d_in[3];
  const float* w_attn = (const float*)d_in[4];
  const float* b_attn = (const float*)d_in[5];
  const float* w_proj = (const float*)d_in[6];
  const float* b_proj = (const float*)d_in[7];
  const float* ln2_g  = (const float*)d_in[8];
  const float* ln2_b  = (const float*)d_in[9];
  const float* w_fc   = (const float*)d_in[10];
  const float* b_fc   = (const float*)d_in[11];
  const float* w_fc2  = (const float*)d_in[12];
  const float* b_fc2  = (const float*)d_in[13];
  float* out = (float*)d_out;

  char* ws = (char*)d_ws;
  size_t off = 0;
  auto alloc = [&](size_t bytes) {
    void* p = ws + off;
    off += (bytes + 255) & ~(size_t)255;
    return p;
  };
  bf16* wT_attn = (bf16*)alloc((size_t)(3 * DM) * DM * 2);
  bf16* wT_proj = (bf16*)alloc((size_t)DM * DM * 2);
  bf16* wT_fc   = (bf16*)alloc((size_t)DFF * DM * 2);
  bf16* wT_fc2  = (bf16*)alloc((size_t)DM * DFF * 2);
  bf16* h       = (bf16*)alloc((size_t)NTOK * DM * 2);        // 12.58 MB
  bf16* qkv     = (bf16*)alloc((size_t)NTOK * (3 * DM) * 2);  // 37.75 MB, contiguous after h
  bf16* vt      = (bf16*)alloc((size_t)BATCH * NH * HDIM * SEQ * 2);
  bf16* x1b     = (bf16*)alloc((size_t)NTOK * DM * 2);
  bf16* act     = (bf16*)alloc((size_t)NTOK * DFF * 2);       // 50.33 MB

  // dead-region reuse for split-K bf16 partials (each needs 2*NTOK*DM*2 = 25.2 MB):
  //  - proj partials -> act region (act unwritten until FC)
  //  - FC2 partials  -> h region start (h dead after FC reads it; 25.2 MB fits
  //    in h+qkv which are both dead at that point)
  bf16* partP = (bf16*)act;
  bf16* partF = (bf16*)h;

  // all weight transposes in one dispatch
  transpose4_kernel<<<6912, 256, 0, stream>>>(
      w_attn, wT_attn, w_proj, wT_proj, w_fc, wT_fc, w_fc2, wT_fc2);
  // LN1 (f32 in)
  ln_kernel<<<NTOK, 256, 0, stream>>>(x, ln1_g, ln1_b, h);
  // QKV: 576 tiles
  gemm_kernel<<<576, 512, 0, stream>>>(
      h, DM, wT_attn, b_attn, nullptr, nullptr, nullptr, qkv, 3 * DM, DM, 0);
  // V transpose (coalesced LDS-tiled)
  vtrans_kernel<<<dim3(SEQ / 64, BATCH * NH), 256, 0, stream>>>(qkv, vt);
  // flash attention (writes O into Q region of qkv)
  attn_kernel<<<BATCH * NH * (SEQ / 64), 256, 0, stream>>>(qkv, vt, pad);
  // proj split-K x2: 384 blocks -> raw bf16 partials (no bias/resid yet)
  gemm_kernel<<<384, 512, 0, stream>>>(
      qkv, 3 * DM, wT_proj, nullptr, nullptr, nullptr, nullptr, partP, DM, DM, 2);
  // proj reduce (+bias +resid x) fused with LN2 -> x1b (bf16) + h (LN2 out)
  reduce_ln_kernel<<<NTOK, 256, 0, stream>>>(
      partP, partP + (size_t)NTOK * DM, b_proj, x, ln2_g, ln2_b, x1b, h);
  // FC + gelu -> act (bf16): 768 tiles
  gemm_kernel<<<768, 512, 0, stream>>>(
      h, DM, wT_fc, b_fc, nullptr, nullptr, nullptr, act, DFF, DM, 1);
  // FC2 split-K x2: 384 blocks -> raw bf16 partials into h region
  gemm_kernel<<<384, 512, 0, stream>>>(
      act, DFF, wT_fc2, nullptr, nullptr, nullptr, nullptr, partF, DM, DFF, 2);
  // FC2 reduce (+bias +resid x1b) -> out (f32)
  reduce_out_kernel<<<(NTOK * DM) / (4 * 256), 256, 0, stream>>>(
      partF, partF + (size_t)NTOK * DM, b_fc2, x1b, out);
}

// Round 13
// 280.971 us; speedup vs baseline: 1.1134x; 1.0092x over previous
//
#include <hip/hip_runtime.h>
#include <hip/hip_bf16.h>

typedef __bf16 bf16;
typedef __bf16 bf16x8 __attribute__((ext_vector_type(8)));
typedef __bf16 bf16x4 __attribute__((ext_vector_type(4)));
typedef float f32x4 __attribute__((ext_vector_type(4)));

#define SEQ 1024
#define BATCH 8
#define DM 768
#define NH 12
#define HDIM 64
#define DFF 3072
#define NTOK (BATCH*SEQ)

#define AS1 __attribute__((address_space(1)))
#define AS3 __attribute__((address_space(3)))
#define MFMA16(a, b, c) __builtin_amdgcn_mfma_f32_16x16x32_bf16(a, b, c, 0, 0, 0)

// exact tanh-gelu via sigmoid identity: 0.5*(1+tanh(z)) = 1/(1+exp(-2z))
__device__ __forceinline__ float gelu_f(float x) {
  const float c = 0.7978845608028654f;
  float z = c * (x + 0.044715f * x * x * x);
  return x / (1.0f + __expf(-2.0f * z));
}

// FUSED prep (R13): LN1 (blocks 0..8191) + all four weight transposes
// (blocks 8192..15103) in ONE dispatch. Both are memory-bound with ragged
// tails; fusing overlaps them and removes a launch gap. Whole-block
// branching (no divergence); LDS overlaid via one shared buffer.
__global__ __launch_bounds__(256) void prep_kernel(
    const float* __restrict__ x, const float* __restrict__ g,
    const float* __restrict__ bta, bf16* __restrict__ h,
    const float* __restrict__ in0, bf16* __restrict__ out0,   // w_attn 768x2304
    const float* __restrict__ in1, bf16* __restrict__ out1,   // w_proj 768x768
    const float* __restrict__ in2, bf16* __restrict__ out2,   // w_fc   768x3072
    const float* __restrict__ in3, bf16* __restrict__ out3) { // w_fc2  3072x768
  __shared__ float smem[32 * 33];   // transpose tile; LN uses smem[0..7]
  int id = blockIdx.x;
  int tid = threadIdx.x;
  if (id < NTOK) {
    // ---- LayerNorm fp32 row -> bf16 ----
    const float* xr = x + (size_t)id * DM;
    float v0 = xr[tid], v1 = xr[tid + 256], v2 = xr[tid + 512];
    float s1 = v0 + v1 + v2;
    float s2 = v0 * v0 + v1 * v1 + v2 * v2;
    #pragma unroll
    for (int m = 32; m >= 1; m >>= 1) {
      s1 += __shfl_xor(s1, m, 64);
      s2 += __shfl_xor(s2, m, 64);
    }
    int wid = tid >> 6;
    if ((tid & 63) == 0) { smem[wid] = s1; smem[4 + wid] = s2; }
    __syncthreads();
    float t1 = smem[0] + smem[1] + smem[2] + smem[3];
    float t2 = smem[4] + smem[5] + smem[6] + smem[7];
    float mean = t1 * (1.0f / DM);
    float var = t2 * (1.0f / DM) - mean * mean;
    float rstd = rsqrtf(var + 1e-5f);
    bf16* orow = h + (size_t)id * DM;
    orow[tid]       = (bf16)((v0 - mean) * rstd * g[tid]       + bta[tid]);
    orow[tid + 256] = (bf16)((v1 - mean) * rstd * g[tid + 256] + bta[tid + 256]);
    orow[tid + 512] = (bf16)((v2 - mean) * rstd * g[tid + 512] + bta[tid + 512]);
  } else {
    // ---- weight transpose fp32[R][C] -> bf16[C][R] ----
    id -= NTOK;
    const float* in; bf16* out; int R, C;
    if (id < 1728)      { in = in0; out = out0; R = 768;  C = 2304; }
    else if (id < 2304) { in = in1; out = out1; R = 768;  C = 768;  id -= 1728; }
    else if (id < 4608) { in = in2; out = out2; R = 768;  C = 3072; id -= 2304; }
    else                { in = in3; out = out3; R = 3072; C = 768;  id -= 4608; }
    float (*tile)[33] = (float(*)[33])smem;
    int nc = C >> 5;
    int c0 = (id % nc) * 32, r0 = (id / nc) * 32;
    int tx = tid & 31, ty = tid >> 5;  // 32 x 8
    #pragma unroll
    for (int i = 0; i < 4; ++i)
      tile[ty + i * 8][tx] = in[(size_t)(r0 + ty + i * 8) * C + c0 + tx];
    __syncthreads();
    #pragma unroll
    for (int i = 0; i < 4; ++i)
      out[(size_t)(c0 + ty + i * 8) * R + r0 + tx] = (bf16)tile[tx][ty + i * 8];
  }
}

// proj split-K reduce fused with LN2 (bf16 partials, vectorized bf16x4):
// x1b = bf16(p0 + p1 + b_proj + x);  h = LN(x1b_f32)*g + b   (stats in f32)
__global__ __launch_bounds__(256) void reduce_ln_kernel(
    const bf16* __restrict__ p0, const bf16* __restrict__ p1,
    const float* __restrict__ bias, const float* __restrict__ resid,
    const float* __restrict__ g, const float* __restrict__ bta,
    bf16* __restrict__ x1b, bf16* __restrict__ h) {
  int row = blockIdx.x;
  int tid = threadIdx.x;
  size_t base = (size_t)row * DM;
  float v[4] = {0.f, 0.f, 0.f, 0.f};
  if (tid < 192) {
    bf16x4 a  = *(const bf16x4*)(p0 + base + tid * 4);
    bf16x4 b  = *(const bf16x4*)(p1 + base + tid * 4);
    f32x4  rs = *(const f32x4*)(resid + base + tid * 4);
    f32x4  bs = *(const f32x4*)(bias + tid * 4);
    bf16x4 o;
    #pragma unroll
    for (int j = 0; j < 4; ++j) {
      v[j] = (float)a[j] + (float)b[j] + bs[j] + rs[j];
      o[j] = (bf16)v[j];
    }
    *(bf16x4*)(x1b + base + tid * 4) = o;
  }
  float s1 = (v[0] + v[1]) + (v[2] + v[3]);
  float s2 = (v[0] * v[0] + v[1] * v[1]) + (v[2] * v[2] + v[3] * v[3]);
  #pragma unroll
  for (int m = 32; m >= 1; m >>= 1) {
    s1 += __shfl_xor(s1, m, 64);
    s2 += __shfl_xor(s2, m, 64);
  }
  __shared__ float ps1[4], ps2[4];
  int wid = tid >> 6;
  if ((tid & 63) == 0) { ps1[wid] = s1; ps2[wid] = s2; }
  __syncthreads();
  float t1 = ps1[0] + ps1[1] + ps1[2] + ps1[3];
  float t2 = ps2[0] + ps2[1] + ps2[2] + ps2[3];
  float mean = t1 * (1.0f / DM);
  float var = t2 * (1.0f / DM) - mean * mean;
  float rstd = rsqrtf(var + 1e-5f);
  if (tid < 192) {
    bf16x4 o;
    #pragma unroll
    for (int j = 0; j < 4; ++j)
      o[j] = (bf16)((v[j] - mean) * rstd * g[tid * 4 + j] + bta[tid * 4 + j]);
    *(bf16x4*)(h + base + tid * 4) = o;
  }
}

// FC2 split-K reduce (bf16 partials): out_f32 = p0 + p1 + b_fc2[col] + x1b(bf16)
__global__ __launch_bounds__(256) void reduce_out_kernel(
    const bf16* __restrict__ p0, const bf16* __restrict__ p1,
    const float* __restrict__ bias, const bf16* __restrict__ resid,
    float* __restrict__ out) {
  int i = blockIdx.x * 256 + threadIdx.x;   // vec4 index; grid covers NTOK*DM/4
  size_t e = (size_t)i * 4;
  bf16x4 a = *(const bf16x4*)(p0 + e);
  bf16x4 b = *(const bf16x4*)(p1 + e);
  f32x4 bs = *(const f32x4*)(bias + (int)(e % DM));
  bf16x4 r = *(const bf16x4*)(resid + e);
  f32x4 o;
  #pragma unroll
  for (int j = 0; j < 4; ++j) o[j] = (float)a[j] + (float)b[j] + bs[j] + (float)r[j];
  *(f32x4*)(out + e) = o;
}

// C[M,N] = A[M,K] @ BT[N,K]^T + bias (+residF f32 | +residB bf16) (+gelu).
// 128x256 tile, BK=32, 8 waves (2Mx4N), wave-tile 64x64, acc[4][4].
// 3-buffer rotation, single barrier per K-step, counted vmcnt(3).
// FINAL structure-family verdict (R2-R10): this is the verified optimum.
//  - 3 blocks/CU of 8-wave blocks: register-impossible (R2: spill, 439us)
//  - 4-wave 128^2 at same residency: worse per-block efficiency (R3: 86us)
//  - 256^2 1-block/CU, coarse schedule: latency-exposed (R7: 82us)
//  - 256^2 1-block/CU, 8-phase fine schedule: still serialized (R10: 94us)
//  - barrier count: neutral (R5); single barrier kept (marginally best)
//  - split-K x2 for N=768 GEMMs + L3-hot reduce: wins (R5 vs R8: 91->77us)
//  - dedicated vtrans beats fused-V scattered epilogue (R1 vs R4)
//  - bf16 partials: -5.6us total (R12), absmax unchanged
// The 2-blocks/CU cross-block overlap is what hides staging latency; no
// 1-block schedule expressible here beat it.
// flags bit0 = gelu.
// flags bit1 = split-K x2: col-major decode in XCD swizzle; raw acc ->
//   (outF|outB) + s*M*N; bias/resid applied by the reduce kernel.
__global__ __launch_bounds__(512, 4) void gemm_kernel(
    const bf16* __restrict__ A, int lda, const bf16* __restrict__ BT,
    const float* __restrict__ bias, const float* __restrict__ residF,
    const bf16* __restrict__ residB,
    float* __restrict__ outF, bf16* __restrict__ outB,
    int N, int K, int flags) {
  __shared__ bf16 As[3][128 * 32];
  __shared__ bf16 Bs[3][256 * 32];
  int tid = threadIdx.x;
  int wid = tid >> 6, lane = tid & 63;
  int nct = N >> 8;
  int nwg = gridDim.x;
  int bid = blockIdx.x;
  int lid = ((nwg & 7) == 0) ? ((bid & 7) * (nwg >> 3) + (bid >> 3)) : bid;
  int row0, col0, koff = 0, Keff = K;
  size_t outOff = 0;
  if (flags & 2) {
    int half = nwg >> 1;
    int s = lid / half;
    int r = lid - s * half;
    int nrt = half / nct;              // row tiles
    col0 = (r / nrt) << 8;             // column-major within XCD group
    row0 = (r % nrt) << 7;
    Keff = K >> 1;
    koff = s * Keff;
    outOff = (size_t)s * ((size_t)nrt << 7) * (size_t)N;
  } else {
    row0 = (lid / nct) * 128;
    col0 = (lid % nct) * 256;
  }
  int wm = wid >> 2, wn = wid & 3;
  int fr = lane & 15, fq = lane >> 4;
  f32x4 acc[4][4] = {};

  int srow = tid >> 2;
  int ssl = ((tid & 3) ^ ((tid >> 3) & 3)) * 8;
  const bf16* gA  = A + (size_t)(row0 + srow) * lda + koff + ssl;
  const bf16* gB  = BT + (size_t)(col0 + srow) * K + koff + ssl;
  const bf16* gB2 = gB + (size_t)128 * K;
  int ldsA  = (wid * 16) * 32;          // elems
  int ldsB  = (wid * 16) * 32;
  int ldsB2 = (128 + wid * 16) * 32;

  int RB0 = wn * 64 + 0 * 16 + fr, RB1 = wn * 64 + 1 * 16 + fr;
  int RB2 = wn * 64 + 2 * 16 + fr, RB3 = wn * 64 + 3 * 16 + fr;
  int RA0 = wm * 64 + 0 * 16 + fr, RA1 = wm * 64 + 1 * 16 + fr;
  int RA2 = wm * 64 + 2 * 16 + fr, RA3 = wm * 64 + 3 * 16 + fr;
  int offB0 = RB0 * 32 + (fq ^ ((RB0 >> 1) & 3)) * 8;
  int offB1 = RB1 * 32 + (fq ^ ((RB1 >> 1) & 3)) * 8;
  int offB2 = RB2 * 32 + (fq ^ ((RB2 >> 1) & 3)) * 8;
  int offB3 = RB3 * 32 + (fq ^ ((RB3 >> 1) & 3)) * 8;
  int offA0 = RA0 * 32 + (fq ^ ((RA0 >> 1) & 3)) * 8;
  int offA1 = RA1 * 32 + (fq ^ ((RA1 >> 1) & 3)) * 8;
  int offA2 = RA2 * 32 + (fq ^ ((RA2 >> 1) & 3)) * 8;
  int offA3 = RA3 * 32 + (fq ^ ((RA3 >> 1) & 3)) * 8;

  int nt = Keff >> 5;  // 24 / 96 / 12 / 48: all % 3 == 0

  __builtin_amdgcn_global_load_lds((const AS1 void*)(gA), (AS3 void*)(&As[0][ldsA]), 16, 0, 0);
  __builtin_amdgcn_global_load_lds((const AS1 void*)(gB), (AS3 void*)(&Bs[0][ldsB]), 16, 0, 0);
  __builtin_amdgcn_global_load_lds((const AS1 void*)(gB2), (AS3 void*)(&Bs[0][ldsB2]), 16, 0, 0);
  __builtin_amdgcn_global_load_lds((const AS1 void*)(gA + 32), (AS3 void*)(&As[1][ldsA]), 16, 0, 0);
  __builtin_amdgcn_global_load_lds((const AS1 void*)(gB + 32), (AS3 void*)(&Bs[1][ldsB]), 16, 0, 0);
  __builtin_amdgcn_global_load_lds((const AS1 void*)(gB2 + 32), (AS3 void*)(&Bs[1][ldsB2]), 16, 0, 0);

#define KS(CB, T)                                                              \
  {                                                                            \
    if ((T) == nt - 1) asm volatile("s_waitcnt vmcnt(0)" ::: "memory");        \
    else               asm volatile("s_waitcnt vmcnt(3)" ::: "memory");        \
    __builtin_amdgcn_s_barrier();                                              \
    bf16x8 b0 = *(const bf16x8*)&Bs[CB][offB0];                                \
    bf16x8 b1 = *(const bf16x8*)&Bs[CB][offB1];                                \
    bf16x8 b2 = *(const bf16x8*)&Bs[CB][offB2];                                \
    bf16x8 b3 = *(const bf16x8*)&Bs[CB][offB3];                                \
    bf16x8 a0 = *(const bf16x8*)&As[CB][offA0];                                \
    bf16x8 a1 = *(const bf16x8*)&As[CB][offA1];                                \
    if ((T) + 2 < nt)                                                          \
      __builtin_amdgcn_global_load_lds(                                        \
          (const AS1 void*)(gA + ((T) + 2) * 32),                              \
          (AS3 void*)(&As[((CB) + 2) % 3][ldsA]), 16, 0, 0);                   \
    __builtin_amdgcn_s_setprio(1);                                             \
    acc[0][0] = MFMA16(a0, b0, acc[0][0]); acc[0][1] = MFMA16(a0, b1, acc[0][1]); \
    acc[0][2] = MFMA16(a0, b2, acc[0][2]); acc[0][3] = MFMA16(a0, b3, acc[0][3]); \
    acc[1][0] = MFMA16(a1, b0, acc[1][0]); acc[1][1] = MFMA16(a1, b1, acc[1][1]); \
    acc[1][2] = MFMA16(a1, b2, acc[1][2]); acc[1][3] = MFMA16(a1, b3, acc[1][3]); \
    __builtin_amdgcn_s_setprio(0);                                             \
    bf16x8 a2 = *(const bf16x8*)&As[CB][offA2];                                \
    bf16x8 a3 = *(const bf16x8*)&As[CB][offA3];                                \
    if ((T) + 2 < nt) {                                                        \
      __builtin_amdgcn_global_load_lds(                                        \
          (const AS1 void*)(gB + ((T) + 2) * 32),                              \
          (AS3 void*)(&Bs[((CB) + 2) % 3][ldsB]), 16, 0, 0);                   \
      __builtin_amdgcn_global_load_lds(                                        \
          (const AS1 void*)(gB2 + ((T) + 2) * 32),                             \
          (AS3 void*)(&Bs[((CB) + 2) % 3][ldsB2]), 16, 0, 0);                  \
    }                                                                          \
    __builtin_amdgcn_s_setprio(1);                                             \
    acc[2][0] = MFMA16(a2, b0, acc[2][0]); acc[2][1] = MFMA16(a2, b1, acc[2][1]); \
    acc[2][2] = MFMA16(a2, b2, acc[2][2]); acc[2][3] = MFMA16(a2, b3, acc[2][3]); \
    acc[3][0] = MFMA16(a3, b0, acc[3][0]); acc[3][1] = MFMA16(a3, b1, acc[3][1]); \
    acc[3][2] = MFMA16(a3, b2, acc[3][2]); acc[3][3] = MFMA16(a3, b3, acc[3][3]); \
    __builtin_amdgcn_s_setprio(0);                                             \
  }

  for (int t = 0; t < nt; t += 3) {
    KS(0, t);
    KS(1, t + 1);
    KS(2, t + 2);
  }
#undef KS

  bool gelu = (flags & 1);
  #pragma unroll
  for (int m = 0; m < 4; ++m) {
    #pragma unroll
    for (int n = 0; n < 4; ++n) {
      int col = col0 + wn * 64 + n * 16 + fr;
      float bs = bias ? bias[col] : 0.f;
      #pragma unroll
      for (int r = 0; r < 4; ++r) {
        int row = row0 + wm * 64 + m * 16 + fq * 4 + r;
        float v = acc[m][n][r] + bs;
        if (gelu) v = gelu_f(v);
        if (residF) v += residF[(size_t)row * N + col];
        if (residB) v += (float)residB[(size_t)row * N + col];
        if (outF) outF[outOff + (size_t)row * N + col] = v;
        else outB[outOff + (size_t)row * N + col] = (bf16)v;
      }
    }
  }
}

// V slice of qkv -> vt[bh][hd][n] (LDS-tiled, coalesced both sides --
// measured better than the scattered fused-V GEMM epilogue, R1 vs R4)
__global__ __launch_bounds__(256) void vtrans_kernel(
    const bf16* __restrict__ qkv, bf16* __restrict__ vt) {
  int bh = blockIdx.y;
  int b = bh / NH, h = bh % NH;
  int n0 = blockIdx.x * 64;
  __shared__ bf16 tile[64][65];
  int tx = threadIdx.x & 63, ty = threadIdx.x >> 6;  // 64 x 4
  #pragma unroll
  for (int i = 0; i < 16; ++i) {
    int n = ty + i * 4;
    tile[tx][n] = qkv[(size_t)(b * SEQ + n0 + n) * (3 * DM) + 2 * DM + h * HDIM + tx];
  }
  __syncthreads();
  #pragma unroll
  for (int i = 0; i < 16; ++i) {
    int hd = ty + i * 4;
    vt[((size_t)bh * HDIM + hd) * SEQ + n0 + tx] = tile[hd][tx];
  }
}

// Flash attention: one block per (b,h,64-row q-tile); 4 waves x 16 q-rows.
// K/V LDS double-buffered with counted vmcnt(4) + raw s_barrier.
__global__ __launch_bounds__(256) void attn_kernel(
    bf16* __restrict__ qkv, const bf16* __restrict__ vt,
    const int* __restrict__ pad) {
  __shared__ bf16 Ks[2][64 * 64];
  __shared__ bf16 Vs[2][64 * 64];
  __shared__ bf16 P_lds[4][16 * 72];
  int blk = blockIdx.x;
  int lblk = (blk & 7) * 192 + (blk >> 3);
  int qt = lblk & 15;
  int bh = lblk >> 4;
  int b = bh / NH, h = bh % NH;
  int tid = threadIdx.x, wid = tid >> 6, lane = tid & 63;
  int q0 = qt * 64 + wid * 16;
  int fr = lane & 15;
  int fq = lane >> 4;
  int fk = fq * 8;
  const bf16* qbase = qkv + (size_t)(b * SEQ + q0) * (3 * DM) + h * HDIM;
  bf16* Pw = &P_lds[wid][0];
  bf16x8 qf[2];
  #pragma unroll
  for (int kk = 0; kk < 2; ++kk)
    qf[kk] = *(const bf16x8*)(qbase + (size_t)fr * (3 * DM) + kk * 32 + fk);
  int srow = (wid << 4) + (lane >> 3);
  int sc = ((lane & 7) << 4) ^ ((lane >> 3) << 4);
  const bf16* kSrc = qkv + (size_t)(b * SEQ + srow) * (3 * DM) + DM + h * HDIM + (sc >> 1);
  const bf16* vSrc = vt + ((size_t)bh * HDIM + srow) * SEQ + (sc >> 1);

  auto STAGE = [&](int buf, int kt) {
    const bf16* kS = kSrc + (size_t)kt * 64 * (3 * DM);
    const bf16* vS = vSrc + kt * 64;
    bf16* kD = &Ks[buf][wid * 1024];
    bf16* vD = &Vs[buf][wid * 1024];
    __builtin_amdgcn_global_load_lds((const AS1 void*)kS, (AS3 void*)kD, 16, 0, 0);
    __builtin_amdgcn_global_load_lds((const AS1 void*)(kS + 8 * (3 * DM)), (AS3 void*)(kD + 512), 16, 0, 0);
    __builtin_amdgcn_global_load_lds((const AS1 void*)vS, (AS3 void*)vD, 16, 0, 0);
    __builtin_amdgcn_global_load_lds((const AS1 void*)(vS + 8 * SEQ), (AS3 void*)(vD + 512), 16, 0, 0);
  };

  float lp[4] = {0.f, 0.f, 0.f, 0.f};
  f32x4 oacc[4] = {};
  int padv[4];
  #pragma unroll
  for (int r = 0; r < 4; ++r) padv[r] = pad[b * SEQ + q0 + fq * 4 + r];
  bool anymask = __any(padv[0] == 0 || padv[1] == 0 || padv[2] == 0 || padv[3] == 0);
  int xr = (fr & 7) << 4;

  STAGE(0, 0);
  for (int kt = 0; kt < 16; ++kt) {
    int cur = kt & 1;
    if (kt < 15) STAGE(cur ^ 1, kt + 1);
    if (kt == 15) asm volatile("s_waitcnt vmcnt(0)" ::: "memory");
    else          asm volatile("s_waitcnt vmcnt(4)" ::: "memory");
    __builtin_amdgcn_s_barrier();

    f32x4 s[4];
    #pragma unroll
    for (int nt = 0; nt < 4; ++nt) {
      f32x4 a = {};
      #pragma unroll
      for (int kk = 0; kk < 2; ++kk) {
        int colb = (kk * 64 + fq * 16) ^ xr;
        bf16x8 kf = *(const bf16x8*)&Ks[cur][(nt * 16 + fr) * 64 + (colb >> 1)];
        a = __builtin_amdgcn_mfma_f32_16x16x32_bf16(qf[kk], kf, a, 0, 0, 0);
      }
      s[nt] = a;
    }
    if (anymask) {
      #pragma unroll
      for (int r = 0; r < 4; ++r)
        if (padv[r] == 0) { s[0][r] = 0.f; s[1][r] = 0.f; s[2][r] = 0.f; s[3][r] = 0.f; }
    }
    #pragma unroll
    for (int nt = 0; nt < 4; ++nt)
      #pragma unroll
      for (int r = 0; r < 4; ++r)
        s[nt][r] = __expf(s[nt][r] * 0.125f);
    #pragma unroll
    for (int r = 0; r < 4; ++r)
      lp[r] += (s[0][r] + s[1][r]) + (s[2][r] + s[3][r]);
    #pragma unroll
    for (int nt = 0; nt < 4; ++nt)
      #pragma unroll
      for (int r = 0; r < 4; ++r)
        Pw[(fq * 4 + r) * 72 + nt * 16 + fr] = (bf16)s[nt][r];
    #pragma unroll
    for (int nt = 0; nt < 4; ++nt) {
      #pragma unroll
      for (int ks = 0; ks < 2; ++ks) {
        bf16x8 pf = *(const bf16x8*)&Pw[fr * 72 + ks * 32 + fk];
        int colb = (ks * 64 + fq * 16) ^ xr;
        bf16x8 vf = *(const bf16x8*)&Vs[cur][(nt * 16 + fr) * 64 + (colb >> 1)];
        oacc[nt] = __builtin_amdgcn_mfma_f32_16x16x32_bf16(pf, vf, oacc[nt], 0, 0, 0);
      }
    }
    __builtin_amdgcn_s_barrier();
  }
  #pragma unroll
  for (int r = 0; r < 4; ++r) {
    float l = lp[r];
    #pragma unroll
    for (int msk = 8; msk >= 1; msk >>= 1) l += __shfl_xor(l, msk, 64);
    float inv = 1.0f / l;
    #pragma unroll
    for (int nt = 0; nt < 4; ++nt)
      qkv[(size_t)(b * SEQ + q0 + fq * 4 + r) * (3 * DM) + h * HDIM + nt * 16 + fr] =
          (bf16)(oacc[nt][r] * inv);
  }
}

extern "C" void kernel_launch(void* const* d_in, const int* in_sizes, int n_in,
                              void* d_out, int out_size, void* d_ws, size_t ws_size,
                              hipStream_t stream) {
  const float* x      = (const float*)d_in[0];
  const int*   pad    = (const int*)d_in[1];
  const float* ln1_g  = (const float*)d_in[2];
  const float* ln1_b  = (const float*)d_in[3];
  const float* w_attn = (const float*)d_in[4];
  const float* b_attn = (const float*)d_in[5];
  const float* w_proj = (const float*)d_in[6];
  const float* b_proj = (const float*)d_in[7];
  const float* ln2_g  = (const float*)d_in[8];
  const float* ln2_b  = (const float*)d_in[9];
  const float* w_fc   = (const float*)d_in[10];
  const float* b_fc   = (const float*)d_in[11];
  const float* w_fc2  = (const float*)d_in[12];
  const float* b_fc2  = (const float*)d_in[13];
  float* out = (float*)d_out;

  char* ws = (char*)d_ws;
  size_t off = 0;
  auto alloc = [&](size_t bytes) {
    void* p = ws + off;
    off += (bytes + 255) & ~(size_t)255;
    return p;
  };
  bf16* wT_attn = (bf16*)alloc((size_t)(3 * DM) * DM * 2);
  bf16* wT_proj = (bf16*)alloc((size_t)DM * DM * 2);
  bf16* wT_fc   = (bf16*)alloc((size_t)DFF * DM * 2);
  bf16* wT_fc2  = (bf16*)alloc((size_t)DM * DFF * 2);
  bf16* h       = (bf16*)alloc((size_t)NTOK * DM * 2);        // 12.58 MB
  bf16* qkv     = (bf16*)alloc((size_t)NTOK * (3 * DM) * 2);  // 37.75 MB, contiguous after h
  bf16* vt      = (bf16*)alloc((size_t)BATCH * NH * HDIM * SEQ * 2);
  bf16* x1b     = (bf16*)alloc((size_t)NTOK * DM * 2);
  bf16* act     = (bf16*)alloc((size_t)NTOK * DFF * 2);       // 50.33 MB

  // dead-region reuse for split-K bf16 partials (each needs 2*NTOK*DM*2 = 25.2 MB):
  //  - proj partials -> act region (act unwritten until FC)
  //  - FC2 partials  -> h region start (h dead after FC reads it; 25.2 MB fits
  //    in h+qkv which are both dead at that point)
  bf16* partP = (bf16*)act;
  bf16* partF = (bf16*)h;

  // LN1 + all weight transposes, fused into one dispatch (R13)
  prep_kernel<<<NTOK + 6912, 256, 0, stream>>>(
      x, ln1_g, ln1_b, h,
      w_attn, wT_attn, w_proj, wT_proj, w_fc, wT_fc, w_fc2, wT_fc2);
  // QKV: 576 tiles
  gemm_kernel<<<576, 512, 0, stream>>>(
      h, DM, wT_attn, b_attn, nullptr, nullptr, nullptr, qkv, 3 * DM, DM, 0);
  // V transpose (coalesced LDS-tiled)
  vtrans_kernel<<<dim3(SEQ / 64, BATCH * NH), 256, 0, stream>>>(qkv, vt);
  // flash attention (writes O into Q region of qkv)
  attn_kernel<<<BATCH * NH * (SEQ / 64), 256, 0, stream>>>(qkv, vt, pad);
  // proj split-K x2: 384 blocks -> raw bf16 partials (no bias/resid yet)
  gemm_kernel<<<384, 512, 0, stream>>>(
      qkv, 3 * DM, wT_proj, nullptr, nullptr, nullptr, nullptr, partP, DM, DM, 2);
  // proj reduce (+bias +resid x) fused with LN2 -> x1b (bf16) + h (LN2 out)
  reduce_ln_kernel<<<NTOK, 256, 0, stream>>>(
      partP, partP + (size_t)NTOK * DM, b_proj, x, ln2_g, ln2_b, x1b, h);
  // FC + gelu -> act (bf16): 768 tiles
  gemm_kernel<<<768, 512, 0, stream>>>(
      h, DM, wT_fc, b_fc, nullptr, nullptr, nullptr, act, DFF, DM, 1);
  // FC2 split-K x2: 384 blocks -> raw bf16 partials into h region
  gemm_kernel<<<384, 512, 0, stream>>>(
      act, DFF, wT_fc2, nullptr, nullptr, nullptr, nullptr, partF, DM, DFF, 2);
  // FC2 reduce (+bias +resid x1b) -> out (f32)
  reduce_out_kernel<<<(NTOK * DM) / (4 * 256), 256, 0, stream>>>(
      partF, partF + (size_t)NTOK * DM, b_fc2, x1b, out);
}